// Round 12
// baseline (322.867 us; speedup 1.0000x reference)
//
#include <hip/hip_runtime.h>

// ---------------------------------------------------------------------------
// equinet F* pipeline on MI355X.
// R12: butterfly = R9 (proven 300us config). GEMM v4: BK=32, split prefetch
// depths — B (HBM, ~900cy) triple-buffered depth-2; A (L2 yg, ~200cy)
// double-buffered late-store depth-1. LDS 55->35KB => 4 blocks/CU.
// ---------------------------------------------------------------------------

typedef _Float16 f16;
typedef __attribute__((ext_vector_type(8))) short sx8;
typedef __attribute__((ext_vector_type(4))) float fx4;
typedef __attribute__((ext_vector_type(8))) unsigned short usx8;
typedef __attribute__((ext_vector_type(4))) unsigned short usx4;

__device__ __forceinline__ unsigned short f2bf(float f) {
  unsigned u = __builtin_bit_cast(unsigned, f);
  u = (u + 0x7FFFu + ((u >> 16) & 1u)) >> 16;
  return (unsigned short)u;
}
__device__ __forceinline__ float bf2f(unsigned short h) {
  return __builtin_bit_cast(float, ((unsigned)h) << 16);
}

template<int ID>
__device__ __forceinline__ int rp_apply(int k) {
  if constexpr (ID == 0) { return k; }
  else if constexpr (ID == 3) { return (k & 7) * 8 + (k >> 3); }
  else {
    constexpr int l = (ID == 1) ? 4 : (ID == 2) ? 3 : (ID == 4) ? 2 : (ID == 5) ? 1 : 0;
    constexpr int d = 1 << (5 - l);
    constexpr int m2 = 2 * d;
    int g = k / m2, r = k % m2;
    return g * m2 + (r & 1) * d + (r >> 1);
  }
}

__device__ __forceinline__ void term_decode(int t, int& lm, int& rm,
                                            bool& useXi, bool& toYi) {
  lm = (t < 2) ? t : (t < 4) ? (t + 4) : (t - 2);
  rm = (t >= 2 && t <= 5) ? (lm ^ 1) : lm;
  useXi = (t >= 4);
  toYi = (t >> 1) & 1;
}

#define SMEM_BYTES 36864

// ---------------------------------------------------------------------------
// Phase B helper (R9): one 6x6-block complex layer, terms split over 4 groups.
// ---------------------------------------------------------------------------
__device__ __forceinline__ void layer6(int g, int b, int P, int Q,
                                       const float* __restrict__ wp,
                                       const f16* ldsX, float* Y0, float* Y1,
                                       f16* __restrict__ yr,
                                       f16* __restrict__ yi) {
  int lm0, rm0, lm1, rm1;
  switch (g) {
    case 0:  lm0 = 0; rm0 = 0; lm1 = 1; rm1 = 1; break;
    case 1:  lm0 = 6; rm0 = 7; lm1 = 7; rm1 = 6; break;
    case 2:  lm0 = 2; rm0 = 3; lm1 = 3; rm1 = 2; break;
    default: lm0 = 4; rm0 = 4; lm1 = 5; rm1 = 5; break;
  }
  const int xbase = (g & 2) ? 36 : 0;
  float X[36], Y[36];
#pragma unroll
  for (int k = 0; k < 36; ++k) X[k] = (float)ldsX[(xbase + k) * 128 + b];
#pragma unroll
  for (int k = 0; k < 36; ++k) Y[k] = 0.f;

  for (int tt = 0; tt < 2; ++tt) {
    const int lm = tt ? lm1 : lm0;
    const int rm = tt ? rm1 : rm0;
    const float* Lw = wp + ((size_t)lm * 32 + P) * 36;
    const float* Rw = wp + ((size_t)rm * 32 + Q) * 36;
#pragma unroll
    for (int i = 0; i < 6; ++i) {
      float tk[6] = {0.f, 0.f, 0.f, 0.f, 0.f, 0.f};
#pragma unroll
      for (int j = 0; j < 6; ++j) {
        float xv = X[i * 6 + j];
#pragma unroll
        for (int k = 0; k < 6; ++k) tk[k] += xv * Rw[j * 6 + k];
      }
#pragma unroll
      for (int o = 0; o < 6; ++o) {
        float lv = Lw[i * 6 + o];
#pragma unroll
        for (int k = 0; k < 6; ++k) Y[o * 6 + k] += lv * tk[k];
      }
    }
  }
  __syncthreads();
  if (g == 2) {
#pragma unroll
    for (int k = 0; k < 36; ++k) Y0[k * 128 + b] = Y[k];
  } else if (g == 3) {
#pragma unroll
    for (int k = 0; k < 36; ++k) Y1[k * 128 + b] = Y[k];
  }
  __syncthreads();
  if (g == 0) {
#pragma unroll
    for (int k = 0; k < 36; ++k) {
      float v = Y[k] + Y0[k * 128 + b];
      yr[((size_t)((P * 6 + k / 6) * 192 + Q * 6 + k % 6)) * 128 + b] = (f16)v;
    }
  } else if (g == 1) {
#pragma unroll
    for (int k = 0; k < 36; ++k) {
      float v = Y[k] + Y1[k * 128 + b];
      yi[((size_t)((P * 6 + k / 6) * 192 + Q * 6 + k % 6)) * 128 + b] = (f16)v;
    }
  }
}

// ---------------------------------------------------------------------------
// Transpose x (B,128,128,2) fp32 -> xtr/xti (16384, 128) fp16
// ---------------------------------------------------------------------------
__global__ __launch_bounds__(256) void k_transpose(const float* __restrict__ x,
                                                   f16* __restrict__ xtr,
                                                   f16* __restrict__ xti) {
  __shared__ float ls[2][32][129];
  const int t = threadIdx.x;
  const int u = blockIdx.x;
  const int v0 = blockIdx.y * 32;
  for (int it = 0; it < 32; ++it) {
    int b = it * 4 + (t >> 6);
    int r = t & 63;
    int v = r >> 1, ch = r & 1;
    ls[ch][v][b] = x[(((size_t)b * 128 + u) * 128 + (v0 + v)) * 2 + ch];
  }
  __syncthreads();
  for (int it = 0; it < 32; ++it) {
    int idx = it * 256 + t;
    int ch = idx >> 12;
    int v = (idx >> 7) & 31;
    int b = idx & 127;
    f16* dst = ch ? xti : xtr;
    dst[((size_t)(u * 128 + v0 + v)) * 128 + b] = (f16)ls[ch][v][b];
  }
}

// ---------------------------------------------------------------------------
// V + H1 fused (R9).
// ---------------------------------------------------------------------------
__global__ __launch_bounds__(512, 4) void k_vh(const f16* __restrict__ xtr,
                                               const f16* __restrict__ xti,
                                               f16* __restrict__ yr,
                                               f16* __restrict__ yi,
                                               const float* __restrict__ vp,
                                               const float* __restrict__ hp) {
  __shared__ __align__(16) char smem[SMEM_BYTES];
  f16* ldsX = (f16*)smem;
  float* Y0 = (float*)smem;
  float* Y1 = (float*)(smem + 18432);
  const int t = threadIdx.x;
  const int P = blockIdx.x, Q = blockIdx.y;
  const int g = __builtin_amdgcn_readfirstlane(t >> 7);
  const int b = t & 127;

  const int pp = g >> 1, qq = g & 1;
  const int p = 2 * P + pp, q = 2 * Q + qq;
  float Xr[4], Xi[4];
#pragma unroll
  for (int i = 0; i < 2; ++i)
#pragma unroll
    for (int j = 0; j < 2; ++j) {
      size_t off = ((size_t)((4 * P + 2 * pp + i) * 128 + (4 * Q + 2 * qq + j))) * 128 + b;
      Xr[i * 2 + j] = (float)xtr[off];
      Xi[i * 2 + j] = (float)xti[off];
    }
  float Ar[9], Ai[9];
#pragma unroll
  for (int k = 0; k < 9; ++k) { Ar[k] = 0.f; Ai[k] = 0.f; }
  for (int tt = 0; tt < 8; ++tt) {
    int lm, rm; bool useXi, toYi;
    term_decode(tt, lm, rm, useXi, toYi);
    const float* Lw = vp + ((size_t)lm * 64 + p) * 6;
    const float* Rw = vp + ((size_t)rm * 64 + q) * 6;
#pragma unroll
    for (int i = 0; i < 2; ++i) {
      float x0, x1;
      if (useXi) { x0 = Xi[i * 2 + 0]; x1 = Xi[i * 2 + 1]; }
      else       { x0 = Xr[i * 2 + 0]; x1 = Xr[i * 2 + 1]; }
      float t0 = x0 * Rw[0] + x1 * Rw[3];
      float t1 = x0 * Rw[1] + x1 * Rw[4];
      float t2 = x0 * Rw[2] + x1 * Rw[5];
      if (toYi) {
#pragma unroll
        for (int o = 0; o < 3; ++o) {
          float lv = Lw[i * 3 + o];
          Ai[o*3+0] += lv * t0; Ai[o*3+1] += lv * t1; Ai[o*3+2] += lv * t2;
        }
      } else {
#pragma unroll
        for (int o = 0; o < 3; ++o) {
          float lv = Lw[i * 3 + o];
          Ar[o*3+0] += lv * t0; Ar[o*3+1] += lv * t1; Ar[o*3+2] += lv * t2;
        }
      }
    }
  }
#pragma unroll
  for (int o = 0; o < 3; ++o)
#pragma unroll
    for (int k = 0; k < 3; ++k) {
      int ch = (3 * pp + o) * 6 + (3 * qq + k);
      ldsX[ch * 128 + b] = (f16)Ar[o * 3 + k];
      ldsX[(36 + ch) * 128 + b] = (f16)Ai[o * 3 + k];
    }
  __syncthreads();
  layer6(g, b, P, Q, hp, ldsX, Y0, Y1, yr, yi);
}

// ---------------------------------------------------------------------------
// H/G layer (R9): staged copy + term-split.
// ---------------------------------------------------------------------------
template<int PERM>
__global__ __launch_bounds__(512, 4) void k_hg(const f16* __restrict__ xr,
                                               const f16* __restrict__ xi,
                                               f16* __restrict__ yr,
                                               f16* __restrict__ yi,
                                               const float* __restrict__ wp) {
  __shared__ __align__(16) char smem[SMEM_BYTES];
  f16* ldsX = (f16*)smem;
  float* Y0 = (float*)smem;
  float* Y1 = (float*)(smem + 18432);
  const int t = threadIdx.x;
  const int P = blockIdx.x, Q = blockIdx.y;

  for (int r = 0; r < 3; ++r) {
    int idx = t + r * 512;
    if (idx < 1152) {
      int c = idx >> 4, o8 = (idx & 15) * 8;
      int cc = (c < 36) ? c : c - 36;
      int I = cc / 6, J = cc % 6;
      int grow = rp_apply<PERM>(2 * P + I / 3) * 3 + I % 3;
      int gcol = rp_apply<PERM>(2 * Q + J / 3) * 3 + J % 3;
      const f16* src = (c < 36) ? xr : xi;
      usx8 v = *(const usx8*)(src + ((size_t)(grow * 192 + gcol)) * 128 + o8);
      *(usx8*)(ldsX + c * 128 + o8) = v;
    }
  }
  __syncthreads();
  const int g = __builtin_amdgcn_readfirstlane(t >> 7);
  const int b = t & 127;
  layer6(g, b, P, Q, wp, ldsX, Y0, Y1, yr, yi);
}

// ---------------------------------------------------------------------------
// switch + M1..M3 + G1 (R9).
// ---------------------------------------------------------------------------
__global__ __launch_bounds__(512, 4) void k_mg(const f16* __restrict__ xr,
                                               const f16* __restrict__ xi,
                                               f16* __restrict__ yr,
                                               f16* __restrict__ yi,
                                               const float* __restrict__ mp,
                                               const float* __restrict__ gp) {
  __shared__ __align__(16) char smem[SMEM_BYTES];
  f16* ldsX = (f16*)smem;
  float* Y0 = (float*)smem;
  float* Y1 = (float*)(smem + 18432);
  const int t = threadIdx.x;
  const int P = blockIdx.x, Q = blockIdx.y;
  const int g = __builtin_amdgcn_readfirstlane(t >> 7);
  const int b = t & 127;

  const int aa = g >> 1, bb = g & 1;
  const int p = 2 * P + aa, q = 2 * Q + bb;
  const int prow = rp_apply<3>(p) * 3, pcol = rp_apply<3>(q) * 3;
  float Xr[9], Xi[9];
#pragma unroll
  for (int i = 0; i < 3; ++i)
#pragma unroll
    for (int j = 0; j < 3; ++j) {
      size_t off = ((size_t)((prow + i) * 192 + (pcol + j))) * 128 + b;
      Xr[i * 3 + j] = (float)xr[off];
      Xi[i * 3 + j] = (float)xi[off];
    }
  for (int lk = 0; lk < 3; ++lk) {
    const float* wp = mp + (size_t)lk * (8 * 64 * 9);
    float Yr9[9], Yi9[9];
#pragma unroll
    for (int k = 0; k < 9; ++k) { Yr9[k] = Xr[k]; Yi9[k] = Xi[k]; }
    for (int tt = 0; tt < 8; ++tt) {
      int lm, rm; bool useXi, toYi;
      term_decode(tt, lm, rm, useXi, toYi);
      const float* Lw = wp + ((size_t)lm * 64 + p) * 9;
      const float* Rw = wp + ((size_t)rm * 64 + q) * 9;
#pragma unroll
      for (int i = 0; i < 3; ++i) {
        float x0, x1, x2;
        if (useXi) { x0 = Xi[i*3+0]; x1 = Xi[i*3+1]; x2 = Xi[i*3+2]; }
        else       { x0 = Xr[i*3+0]; x1 = Xr[i*3+1]; x2 = Xr[i*3+2]; }
        float t0 = x0 * Rw[0] + x1 * Rw[3] + x2 * Rw[6];
        float t1 = x0 * Rw[1] + x1 * Rw[4] + x2 * Rw[7];
        float t2 = x0 * Rw[2] + x1 * Rw[5] + x2 * Rw[8];
        if (toYi) {
#pragma unroll
          for (int o = 0; o < 3; ++o) {
            float lv = Lw[i * 3 + o];
            Yi9[o*3+0] += lv * t0; Yi9[o*3+1] += lv * t1; Yi9[o*3+2] += lv * t2;
          }
        } else {
#pragma unroll
          for (int o = 0; o < 3; ++o) {
            float lv = Lw[i * 3 + o];
            Yr9[o*3+0] += lv * t0; Yr9[o*3+1] += lv * t1; Yr9[o*3+2] += lv * t2;
          }
        }
      }
    }
#pragma unroll
    for (int k = 0; k < 9; ++k) { Xr[k] = Yr9[k]; Xi[k] = Yi9[k]; }
  }
#pragma unroll
  for (int i = 0; i < 3; ++i)
#pragma unroll
    for (int j = 0; j < 3; ++j) {
      int ch = (3 * aa + i) * 6 + (3 * bb + j);
      ldsX[ch * 128 + b] = (f16)Xr[i * 3 + j];
      ldsX[(36 + ch) * 128 + b] = (f16)Xi[i * 3 + j];
    }
  __syncthreads();
  layer6(g, b, P, Q, gp, ldsX, Y0, Y1, yr, yi);
}

// ---------------------------------------------------------------------------
// U layer (R9). perm(l=0) on read. Up:(8,64,3,2)
// ---------------------------------------------------------------------------
__global__ __launch_bounds__(128, 2) void k_u(const f16* __restrict__ xr,
                                              const f16* __restrict__ xi,
                                              unsigned short* __restrict__ ut,
                                              const float* __restrict__ wp) {
  const int b = threadIdx.x;
  const int p = blockIdx.x, q = blockIdx.y;
  int rrow[3], rcol[3];
#pragma unroll
  for (int i = 0; i < 3; ++i) {
    rrow[i] = rp_apply<6>(p) * 3 + i;
    rcol[i] = rp_apply<6>(q) * 3 + i;
  }
  float X[9], Y[4] = {0.f, 0.f, 0.f, 0.f};
  auto loadX = [&](const f16* src) {
#pragma unroll
    for (int i = 0; i < 3; ++i)
#pragma unroll
      for (int j = 0; j < 3; ++j)
        X[i * 3 + j] = (float)src[((size_t)(rrow[i] * 192 + rcol[j])) * 128 + b];
  };
  auto term = [&](int lm, int rm) {
    const float* Lw = wp + ((size_t)lm * 64 + p) * 6;
    const float* Rw = wp + ((size_t)rm * 64 + q) * 6;
#pragma unroll
    for (int i = 0; i < 3; ++i) {
      float t0 = X[i*3+0] * Rw[0] + X[i*3+1] * Rw[2] + X[i*3+2] * Rw[4];
      float t1 = X[i*3+0] * Rw[1] + X[i*3+1] * Rw[3] + X[i*3+2] * Rw[5];
      Y[0] += Lw[i*2+0] * t0; Y[1] += Lw[i*2+0] * t1;
      Y[2] += Lw[i*2+1] * t0; Y[3] += Lw[i*2+1] * t1;
    }
  };
  loadX(xr); term(0, 0); term(3, 3);
  loadX(xi); term(4, 5); term(7, 6);
#pragma unroll
  for (int o = 0; o < 2; ++o)
#pragma unroll
    for (int k = 0; k < 2; ++k)
      ut[((size_t)((p * 2 + o) * 128 + (q * 2 + k))) * 128 + b] = f2bf(Y[o * 2 + k]);
}

// ---------------------------------------------------------------------------
// Gather + transpose (R9)
// ---------------------------------------------------------------------------
__global__ __launch_bounds__(256) void k_gather(const unsigned short* __restrict__ ut,
                                                const int* __restrict__ r_index,
                                                unsigned short* __restrict__ yg) {
  __shared__ unsigned short ls[64][130];
  __shared__ int ridx[64];
  const int t = threadIdx.x;
  const int m0 = blockIdx.x * 64;
  if (t < 64) ridx[t] = r_index[m0 + t];
  __syncthreads();
  for (int it = 0; it < 32; ++it) {
    int idx = it * 256 + t;
    int ml = idx >> 7, b = idx & 127;
    ls[ml][b] = ut[(size_t)ridx[ml] * 128 + b];
  }
  __syncthreads();
  int b = t >> 1, half = t & 1;
#pragma unroll
  for (int c = 0; c < 4; ++c) {
    usx8 v;
#pragma unroll
    for (int e = 0; e < 8; ++e) v[e] = ls[half * 32 + c * 8 + e][b];
    *(usx8*)(yg + (size_t)b * 16384 + m0 + half * 32 + c * 8) = v;
  }
}

// ---------------------------------------------------------------------------
// GEMM v4: BK=32; B triple-buffered depth-2 (HBM); A double-buffered
// late-store depth-1 (L2). Grid (8,100), 256 thr, 64 steps, bf16 partial.
// LDS: As 2x128x40 (20KB) + Bs 3x64x40 (15KB) = 35KB -> 4 blocks/CU.
// ---------------------------------------------------------------------------
#define G4_KC 8
#define G4_STEPS 64
#define G4_P 40

__global__ __launch_bounds__(256) void k_gemm4(const unsigned short* __restrict__ yg,
                                               const float* __restrict__ cart,
                                               unsigned short* __restrict__ partial) {
  __shared__ unsigned short As[2][128][G4_P];
  __shared__ unsigned short Bs[3][64][G4_P];
  const int t = threadIdx.x;
  const int lane = t & 63, w = t >> 6;
  const int kc = blockIdx.x;
  const int c0 = blockIdx.y * 64;
  const int k0 = kc * 2048;

  fx4 acc[2][4];
#pragma unroll
  for (int i = 0; i < 2; ++i)
#pragma unroll
    for (int j = 0; j < 4; ++j) acc[i][j] = (fx4)0.f;

  // A: 128 rows x 32 k = 512 chunks of 16B; c = t + rep*256
  auto ldA = [&](int kpos, usx8* a0, usx8* a1) {
    int c0i = t, c1i = t + 256;
    *a0 = *(const usx8*)(yg + (size_t)(c0i >> 2) * 16384 + kpos + (c0i & 3) * 8);
    *a1 = *(const usx8*)(yg + (size_t)(c1i >> 2) * 16384 + kpos + (c1i & 3) * 8);
  };
  auto stA = [&](int buf, usx8 a0, usx8 a1) {
    int c0i = t, c1i = t + 256;
    *(usx8*)(&As[buf][c0i >> 2][(c0i & 3) * 8]) = a0;
    *(usx8*)(&As[buf][c1i >> 2][(c1i & 3) * 8]) = a1;
  };
  // B: 64 rows x 32 k fp32 = 256 chunks of 32B; c = t
  auto ldB = [&](int kpos, fx4* f0, fx4* f1) {
    const float* p = cart + (size_t)(c0 + (t >> 2)) * 16384 + kpos + (t & 3) * 8;
    *f0 = *(const fx4*)p;
    *f1 = *(const fx4*)(p + 4);
  };
  auto stB = [&](int buf, fx4 f0, fx4 f1) {
    usx8 v;
    v[0]=f2bf(f0[0]); v[1]=f2bf(f0[1]); v[2]=f2bf(f0[2]); v[3]=f2bf(f0[3]);
    v[4]=f2bf(f1[0]); v[5]=f2bf(f1[1]); v[6]=f2bf(f1[2]); v[7]=f2bf(f1[3]);
    *(usx8*)(&Bs[buf][t >> 2][(t & 3) * 8]) = v;
  };

  // prologue: tile0 staged; tile1 B (and A) held in regs
  usx8 rA0, rA1; fx4 rB0, rB1;
  {
    usx8 pa0, pa1; fx4 pb0, pb1;
    ldA(k0, &pa0, &pa1); ldB(k0, &pb0, &pb1);
    ldA(k0 + 32, &rA0, &rA1); ldB(k0 + 32, &rB0, &rB1);
    stA(0, pa0, pa1); stB(0, pb0, pb1);
  }
  __syncthreads();

  for (int s = 0; s < G4_STEPS; ++s) {
    const int curA = s & 1, curB = s % 3;
    // (1) store tile s+1 from regs (aged ~1 full step)
    if (s + 1 < G4_STEPS) { stB((s + 1) % 3, rB0, rB1); stA((s + 1) & 1, rA0, rA1); }
    // (2) issue B loads for s+2 (depth-2, HBM) and A loads for s+2 too
    if (s + 2 < G4_STEPS) {
      ldB(k0 + (s + 2) * 32, &rB0, &rB1);
      ldA(k0 + (s + 2) * 32, &rA0, &rA1);
    }
    // (3) fragments from current buffers
    sx8 af[2], bf[4];
#pragma unroll
    for (int mi = 0; mi < 2; ++mi)
      af[mi] = *(const sx8*)(&As[curA][w * 32 + mi * 16 + (lane & 15)][(lane >> 4) * 8]);
#pragma unroll
    for (int ni = 0; ni < 4; ++ni)
      bf[ni] = *(const sx8*)(&Bs[curB][ni * 16 + (lane & 15)][(lane >> 4) * 8]);
#pragma unroll
    for (int mi = 0; mi < 2; ++mi)
#pragma unroll
      for (int ni = 0; ni < 4; ++ni)
        acc[mi][ni] = __builtin_amdgcn_mfma_f32_16x16x32_bf16(af[mi], bf[ni], acc[mi][ni], 0, 0, 0);
    __syncthreads();
  }

  // epilogue: partial[kc][b][c] bf16
#pragma unroll
  for (int mi = 0; mi < 2; ++mi) {
    int brow = w * 32 + mi * 16 + (lane >> 4) * 4;
#pragma unroll
    for (int ni = 0; ni < 4; ++ni) {
      int cc = c0 + ni * 16 + (lane & 15);
#pragma unroll
      for (int r = 0; r < 4; ++r)
        partial[((size_t)kc * 128 + brow + r) * 6400 + cc] = f2bf(acc[mi][ni][r]);
    }
  }
}

__global__ __launch_bounds__(256) void k_reduce2(const unsigned short* __restrict__ partial,
                                                 float* __restrict__ out) {
  int i = blockIdx.x * 256 + threadIdx.x;
  fx4 s = (fx4)0.f;
#pragma unroll
  for (int kc = 0; kc < G4_KC; ++kc) {
    usx4 v = *(const usx4*)(partial + (size_t)kc * 819200 + (size_t)i * 4);
    s[0] += bf2f(v[0]); s[1] += bf2f(v[1]); s[2] += bf2f(v[2]); s[3] += bf2f(v[3]);
  }
  *(fx4*)(out + (size_t)i * 4) = s;
}

// ---------------------------------------------------------------------------
extern "C" void kernel_launch(void* const* d_in, const int* in_sizes, int n_in,
                              void* d_out, int out_size, void* d_ws, size_t ws_size,
                              hipStream_t stream) {
  const float* x    = (const float*)d_in[0];
  const float* Vp   = (const float*)d_in[1];
  const float* Hp   = (const float*)d_in[2];
  const float* Mp   = (const float*)d_in[3];
  const float* Gp   = (const float*)d_in[4];
  const float* Up   = (const float*)d_in[5];
  const float* cart = (const float*)d_in[6];
  const int*   ridx = (const int*)d_in[7];
  float* out = (float*)d_out;
  unsigned short* hb = (unsigned short*)d_ws;

  const size_t PSZ = 4718592;
  f16* P0r = (f16*)(hb);
  f16* P0i = (f16*)(hb + PSZ);
  f16* P1r = (f16*)(hb + 2 * PSZ);
  f16* P1i = (f16*)(hb + 3 * PSZ);
  f16* xtr = (f16*)(hb + 4 * PSZ);
  f16* xti = (f16*)(hb + 4 * PSZ + 2097152);
  unsigned short* ut = hb + 4 * PSZ;
  unsigned short* yg = hb + 4 * PSZ + 2097152;
  unsigned short* partial = hb;

  const size_t HSZ = 8 * 32 * 36;

  k_transpose<<<dim3(128, 4), 256, 0, stream>>>(x, xtr, xti);
  k_vh<<<dim3(32, 32), 512, 0, stream>>>(xtr, xti, P0r, P0i, Vp, Hp + 0 * HSZ);
  k_hg<1><<<dim3(32, 32), 512, 0, stream>>>(P0r, P0i, P1r, P1i, Hp + 1 * HSZ);  // perm(l=4)
  k_hg<2><<<dim3(32, 32), 512, 0, stream>>>(P1r, P1i, P0r, P0i, Hp + 2 * HSZ);  // perm(l=3)
  k_mg<<<dim3(32, 32), 512, 0, stream>>>(P0r, P0i, P1r, P1i, Mp, Gp + 0 * HSZ); // switch+M123+G1
  k_hg<4><<<dim3(32, 32), 512, 0, stream>>>(P1r, P1i, P0r, P0i, Gp + 1 * HSZ);  // perm(l=2)
  k_hg<5><<<dim3(32, 32), 512, 0, stream>>>(P0r, P0i, P1r, P1i, Gp + 2 * HSZ);  // perm(l=1)
  k_u<<<dim3(64, 64), 128, 0, stream>>>(P1r, P1i, ut, Up);                      // perm(l=0) inside
  k_gather<<<dim3(256), 256, 0, stream>>>(ut, ridx, yg);
  k_gemm4<<<dim3(G4_KC, 100), 256, 0, stream>>>(yg, cart, partial);
  k_reduce2<<<dim3(800), 256, 0, stream>>>(partial, out);
  (void)in_sizes; (void)n_in; (void)out_size; (void)ws_size;
}

// Round 13
// 306.134 us; speedup vs baseline: 1.0547x; 1.0547x over previous
//
#include <hip/hip_runtime.h>

// ---------------------------------------------------------------------------
// equinet F* pipeline on MI355X.
// R13: butterfly = R9 verbatim (best known, 300us). GEMM = R9's gemm2 with
// ONE change: As pad removed (pitch 72->64) + XOR chunk swizzle
// (chunk ^= row&7 on both write and read; bank-floor preserved).
// LDS 55.3 -> 50.0 KB => 3 blocks/CU (was 2): +50% concurrency to convert
// the GEMM's latency-stall fraction into achieved HBM bandwidth.
// ---------------------------------------------------------------------------

typedef _Float16 f16;
typedef __attribute__((ext_vector_type(8))) short sx8;
typedef __attribute__((ext_vector_type(4))) float fx4;
typedef __attribute__((ext_vector_type(8))) unsigned short usx8;
typedef __attribute__((ext_vector_type(4))) unsigned short usx4;

__device__ __forceinline__ unsigned short f2bf(float f) {
  unsigned u = __builtin_bit_cast(unsigned, f);
  u = (u + 0x7FFFu + ((u >> 16) & 1u)) >> 16;
  return (unsigned short)u;
}
__device__ __forceinline__ float bf2f(unsigned short h) {
  return __builtin_bit_cast(float, ((unsigned)h) << 16);
}

template<int ID>
__device__ __forceinline__ int rp_apply(int k) {
  if constexpr (ID == 0) { return k; }
  else if constexpr (ID == 3) { return (k & 7) * 8 + (k >> 3); }
  else {
    constexpr int l = (ID == 1) ? 4 : (ID == 2) ? 3 : (ID == 4) ? 2 : (ID == 5) ? 1 : 0;
    constexpr int d = 1 << (5 - l);
    constexpr int m2 = 2 * d;
    int g = k / m2, r = k % m2;
    return g * m2 + (r & 1) * d + (r >> 1);
  }
}

__device__ __forceinline__ void term_decode(int t, int& lm, int& rm,
                                            bool& useXi, bool& toYi) {
  lm = (t < 2) ? t : (t < 4) ? (t + 4) : (t - 2);
  rm = (t >= 2 && t <= 5) ? (lm ^ 1) : lm;
  useXi = (t >= 4);
  toYi = (t >> 1) & 1;
}

#define SMEM_BYTES 36864

// ---------------------------------------------------------------------------
// Phase B helper (R9): one 6x6-block complex layer, terms split over 4 groups.
// ---------------------------------------------------------------------------
__device__ __forceinline__ void layer6(int g, int b, int P, int Q,
                                       const float* __restrict__ wp,
                                       const f16* ldsX, float* Y0, float* Y1,
                                       f16* __restrict__ yr,
                                       f16* __restrict__ yi) {
  int lm0, rm0, lm1, rm1;
  switch (g) {
    case 0:  lm0 = 0; rm0 = 0; lm1 = 1; rm1 = 1; break;
    case 1:  lm0 = 6; rm0 = 7; lm1 = 7; rm1 = 6; break;
    case 2:  lm0 = 2; rm0 = 3; lm1 = 3; rm1 = 2; break;
    default: lm0 = 4; rm0 = 4; lm1 = 5; rm1 = 5; break;
  }
  const int xbase = (g & 2) ? 36 : 0;
  float X[36], Y[36];
#pragma unroll
  for (int k = 0; k < 36; ++k) X[k] = (float)ldsX[(xbase + k) * 128 + b];
#pragma unroll
  for (int k = 0; k < 36; ++k) Y[k] = 0.f;

  for (int tt = 0; tt < 2; ++tt) {
    const int lm = tt ? lm1 : lm0;
    const int rm = tt ? rm1 : rm0;
    const float* Lw = wp + ((size_t)lm * 32 + P) * 36;
    const float* Rw = wp + ((size_t)rm * 32 + Q) * 36;
#pragma unroll
    for (int i = 0; i < 6; ++i) {
      float tk[6] = {0.f, 0.f, 0.f, 0.f, 0.f, 0.f};
#pragma unroll
      for (int j = 0; j < 6; ++j) {
        float xv = X[i * 6 + j];
#pragma unroll
        for (int k = 0; k < 6; ++k) tk[k] += xv * Rw[j * 6 + k];
      }
#pragma unroll
      for (int o = 0; o < 6; ++o) {
        float lv = Lw[i * 6 + o];
#pragma unroll
        for (int k = 0; k < 6; ++k) Y[o * 6 + k] += lv * tk[k];
      }
    }
  }
  __syncthreads();
  if (g == 2) {
#pragma unroll
    for (int k = 0; k < 36; ++k) Y0[k * 128 + b] = Y[k];
  } else if (g == 3) {
#pragma unroll
    for (int k = 0; k < 36; ++k) Y1[k * 128 + b] = Y[k];
  }
  __syncthreads();
  if (g == 0) {
#pragma unroll
    for (int k = 0; k < 36; ++k) {
      float v = Y[k] + Y0[k * 128 + b];
      yr[((size_t)((P * 6 + k / 6) * 192 + Q * 6 + k % 6)) * 128 + b] = (f16)v;
    }
  } else if (g == 1) {
#pragma unroll
    for (int k = 0; k < 36; ++k) {
      float v = Y[k] + Y1[k * 128 + b];
      yi[((size_t)((P * 6 + k / 6) * 192 + Q * 6 + k % 6)) * 128 + b] = (f16)v;
    }
  }
}

// ---------------------------------------------------------------------------
// Transpose x (B,128,128,2) fp32 -> xtr/xti (16384, 128) fp16
// ---------------------------------------------------------------------------
__global__ __launch_bounds__(256) void k_transpose(const float* __restrict__ x,
                                                   f16* __restrict__ xtr,
                                                   f16* __restrict__ xti) {
  __shared__ float ls[2][32][129];
  const int t = threadIdx.x;
  const int u = blockIdx.x;
  const int v0 = blockIdx.y * 32;
  for (int it = 0; it < 32; ++it) {
    int b = it * 4 + (t >> 6);
    int r = t & 63;
    int v = r >> 1, ch = r & 1;
    ls[ch][v][b] = x[(((size_t)b * 128 + u) * 128 + (v0 + v)) * 2 + ch];
  }
  __syncthreads();
  for (int it = 0; it < 32; ++it) {
    int idx = it * 256 + t;
    int ch = idx >> 12;
    int v = (idx >> 7) & 31;
    int b = idx & 127;
    f16* dst = ch ? xti : xtr;
    dst[((size_t)(u * 128 + v0 + v)) * 128 + b] = (f16)ls[ch][v][b];
  }
}

// ---------------------------------------------------------------------------
// V + H1 fused (R9).
// ---------------------------------------------------------------------------
__global__ __launch_bounds__(512, 4) void k_vh(const f16* __restrict__ xtr,
                                               const f16* __restrict__ xti,
                                               f16* __restrict__ yr,
                                               f16* __restrict__ yi,
                                               const float* __restrict__ vp,
                                               const float* __restrict__ hp) {
  __shared__ __align__(16) char smem[SMEM_BYTES];
  f16* ldsX = (f16*)smem;
  float* Y0 = (float*)smem;
  float* Y1 = (float*)(smem + 18432);
  const int t = threadIdx.x;
  const int P = blockIdx.x, Q = blockIdx.y;
  const int g = __builtin_amdgcn_readfirstlane(t >> 7);
  const int b = t & 127;

  const int pp = g >> 1, qq = g & 1;
  const int p = 2 * P + pp, q = 2 * Q + qq;
  float Xr[4], Xi[4];
#pragma unroll
  for (int i = 0; i < 2; ++i)
#pragma unroll
    for (int j = 0; j < 2; ++j) {
      size_t off = ((size_t)((4 * P + 2 * pp + i) * 128 + (4 * Q + 2 * qq + j))) * 128 + b;
      Xr[i * 2 + j] = (float)xtr[off];
      Xi[i * 2 + j] = (float)xti[off];
    }
  float Ar[9], Ai[9];
#pragma unroll
  for (int k = 0; k < 9; ++k) { Ar[k] = 0.f; Ai[k] = 0.f; }
  for (int tt = 0; tt < 8; ++tt) {
    int lm, rm; bool useXi, toYi;
    term_decode(tt, lm, rm, useXi, toYi);
    const float* Lw = vp + ((size_t)lm * 64 + p) * 6;
    const float* Rw = vp + ((size_t)rm * 64 + q) * 6;
#pragma unroll
    for (int i = 0; i < 2; ++i) {
      float x0, x1;
      if (useXi) { x0 = Xi[i * 2 + 0]; x1 = Xi[i * 2 + 1]; }
      else       { x0 = Xr[i * 2 + 0]; x1 = Xr[i * 2 + 1]; }
      float t0 = x0 * Rw[0] + x1 * Rw[3];
      float t1 = x0 * Rw[1] + x1 * Rw[4];
      float t2 = x0 * Rw[2] + x1 * Rw[5];
      if (toYi) {
#pragma unroll
        for (int o = 0; o < 3; ++o) {
          float lv = Lw[i * 3 + o];
          Ai[o*3+0] += lv * t0; Ai[o*3+1] += lv * t1; Ai[o*3+2] += lv * t2;
        }
      } else {
#pragma unroll
        for (int o = 0; o < 3; ++o) {
          float lv = Lw[i * 3 + o];
          Ar[o*3+0] += lv * t0; Ar[o*3+1] += lv * t1; Ar[o*3+2] += lv * t2;
        }
      }
    }
  }
#pragma unroll
  for (int o = 0; o < 3; ++o)
#pragma unroll
    for (int k = 0; k < 3; ++k) {
      int ch = (3 * pp + o) * 6 + (3 * qq + k);
      ldsX[ch * 128 + b] = (f16)Ar[o * 3 + k];
      ldsX[(36 + ch) * 128 + b] = (f16)Ai[o * 3 + k];
    }
  __syncthreads();
  layer6(g, b, P, Q, hp, ldsX, Y0, Y1, yr, yi);
}

// ---------------------------------------------------------------------------
// H/G layer (R9): staged copy + term-split.
// ---------------------------------------------------------------------------
template<int PERM>
__global__ __launch_bounds__(512, 4) void k_hg(const f16* __restrict__ xr,
                                               const f16* __restrict__ xi,
                                               f16* __restrict__ yr,
                                               f16* __restrict__ yi,
                                               const float* __restrict__ wp) {
  __shared__ __align__(16) char smem[SMEM_BYTES];
  f16* ldsX = (f16*)smem;
  float* Y0 = (float*)smem;
  float* Y1 = (float*)(smem + 18432);
  const int t = threadIdx.x;
  const int P = blockIdx.x, Q = blockIdx.y;

  for (int r = 0; r < 3; ++r) {
    int idx = t + r * 512;
    if (idx < 1152) {
      int c = idx >> 4, o8 = (idx & 15) * 8;
      int cc = (c < 36) ? c : c - 36;
      int I = cc / 6, J = cc % 6;
      int grow = rp_apply<PERM>(2 * P + I / 3) * 3 + I % 3;
      int gcol = rp_apply<PERM>(2 * Q + J / 3) * 3 + J % 3;
      const f16* src = (c < 36) ? xr : xi;
      usx8 v = *(const usx8*)(src + ((size_t)(grow * 192 + gcol)) * 128 + o8);
      *(usx8*)(ldsX + c * 128 + o8) = v;
    }
  }
  __syncthreads();
  const int g = __builtin_amdgcn_readfirstlane(t >> 7);
  const int b = t & 127;
  layer6(g, b, P, Q, wp, ldsX, Y0, Y1, yr, yi);
}

// ---------------------------------------------------------------------------
// switch + M1..M3 + G1 (R9).
// ---------------------------------------------------------------------------
__global__ __launch_bounds__(512, 4) void k_mg(const f16* __restrict__ xr,
                                               const f16* __restrict__ xi,
                                               f16* __restrict__ yr,
                                               f16* __restrict__ yi,
                                               const float* __restrict__ mp,
                                               const float* __restrict__ gp) {
  __shared__ __align__(16) char smem[SMEM_BYTES];
  f16* ldsX = (f16*)smem;
  float* Y0 = (float*)smem;
  float* Y1 = (float*)(smem + 18432);
  const int t = threadIdx.x;
  const int P = blockIdx.x, Q = blockIdx.y;
  const int g = __builtin_amdgcn_readfirstlane(t >> 7);
  const int b = t & 127;

  const int aa = g >> 1, bb = g & 1;
  const int p = 2 * P + aa, q = 2 * Q + bb;
  const int prow = rp_apply<3>(p) * 3, pcol = rp_apply<3>(q) * 3;
  float Xr[9], Xi[9];
#pragma unroll
  for (int i = 0; i < 3; ++i)
#pragma unroll
    for (int j = 0; j < 3; ++j) {
      size_t off = ((size_t)((prow + i) * 192 + (pcol + j))) * 128 + b;
      Xr[i * 3 + j] = (float)xr[off];
      Xi[i * 3 + j] = (float)xi[off];
    }
  for (int lk = 0; lk < 3; ++lk) {
    const float* wp = mp + (size_t)lk * (8 * 64 * 9);
    float Yr9[9], Yi9[9];
#pragma unroll
    for (int k = 0; k < 9; ++k) { Yr9[k] = Xr[k]; Yi9[k] = Xi[k]; }
    for (int tt = 0; tt < 8; ++tt) {
      int lm, rm; bool useXi, toYi;
      term_decode(tt, lm, rm, useXi, toYi);
      const float* Lw = wp + ((size_t)lm * 64 + p) * 9;
      const float* Rw = wp + ((size_t)rm * 64 + q) * 9;
#pragma unroll
      for (int i = 0; i < 3; ++i) {
        float x0, x1, x2;
        if (useXi) { x0 = Xi[i*3+0]; x1 = Xi[i*3+1]; x2 = Xi[i*3+2]; }
        else       { x0 = Xr[i*3+0]; x1 = Xr[i*3+1]; x2 = Xr[i*3+2]; }
        float t0 = x0 * Rw[0] + x1 * Rw[3] + x2 * Rw[6];
        float t1 = x0 * Rw[1] + x1 * Rw[4] + x2 * Rw[7];
        float t2 = x0 * Rw[2] + x1 * Rw[5] + x2 * Rw[8];
        if (toYi) {
#pragma unroll
          for (int o = 0; o < 3; ++o) {
            float lv = Lw[i * 3 + o];
            Yi9[o*3+0] += lv * t0; Yi9[o*3+1] += lv * t1; Yi9[o*3+2] += lv * t2;
          }
        } else {
#pragma unroll
          for (int o = 0; o < 3; ++o) {
            float lv = Lw[i * 3 + o];
            Yr9[o*3+0] += lv * t0; Yr9[o*3+1] += lv * t1; Yr9[o*3+2] += lv * t2;
          }
        }
      }
    }
#pragma unroll
    for (int k = 0; k < 9; ++k) { Xr[k] = Yr9[k]; Xi[k] = Yi9[k]; }
  }
#pragma unroll
  for (int i = 0; i < 3; ++i)
#pragma unroll
    for (int j = 0; j < 3; ++j) {
      int ch = (3 * aa + i) * 6 + (3 * bb + j);
      ldsX[ch * 128 + b] = (f16)Xr[i * 3 + j];
      ldsX[(36 + ch) * 128 + b] = (f16)Xi[i * 3 + j];
    }
  __syncthreads();
  layer6(g, b, P, Q, gp, ldsX, Y0, Y1, yr, yi);
}

// ---------------------------------------------------------------------------
// U layer (R9). perm(l=0) on read. Up:(8,64,3,2)
// ---------------------------------------------------------------------------
__global__ __launch_bounds__(128, 2) void k_u(const f16* __restrict__ xr,
                                              const f16* __restrict__ xi,
                                              unsigned short* __restrict__ ut,
                                              const float* __restrict__ wp) {
  const int b = threadIdx.x;
  const int p = blockIdx.x, q = blockIdx.y;
  int rrow[3], rcol[3];
#pragma unroll
  for (int i = 0; i < 3; ++i) {
    rrow[i] = rp_apply<6>(p) * 3 + i;
    rcol[i] = rp_apply<6>(q) * 3 + i;
  }
  float X[9], Y[4] = {0.f, 0.f, 0.f, 0.f};
  auto loadX = [&](const f16* src) {
#pragma unroll
    for (int i = 0; i < 3; ++i)
#pragma unroll
      for (int j = 0; j < 3; ++j)
        X[i * 3 + j] = (float)src[((size_t)(rrow[i] * 192 + rcol[j])) * 128 + b];
  };
  auto term = [&](int lm, int rm) {
    const float* Lw = wp + ((size_t)lm * 64 + p) * 6;
    const float* Rw = wp + ((size_t)rm * 64 + q) * 6;
#pragma unroll
    for (int i = 0; i < 3; ++i) {
      float t0 = X[i*3+0] * Rw[0] + X[i*3+1] * Rw[2] + X[i*3+2] * Rw[4];
      float t1 = X[i*3+0] * Rw[1] + X[i*3+1] * Rw[3] + X[i*3+2] * Rw[5];
      Y[0] += Lw[i*2+0] * t0; Y[1] += Lw[i*2+0] * t1;
      Y[2] += Lw[i*2+1] * t0; Y[3] += Lw[i*2+1] * t1;
    }
  };
  loadX(xr); term(0, 0); term(3, 3);
  loadX(xi); term(4, 5); term(7, 6);
#pragma unroll
  for (int o = 0; o < 2; ++o)
#pragma unroll
    for (int k = 0; k < 2; ++k)
      ut[((size_t)((p * 2 + o) * 128 + (q * 2 + k))) * 128 + b] = f2bf(Y[o * 2 + k]);
}

// ---------------------------------------------------------------------------
// Gather + transpose (R9)
// ---------------------------------------------------------------------------
__global__ __launch_bounds__(256) void k_gather(const unsigned short* __restrict__ ut,
                                                const int* __restrict__ r_index,
                                                unsigned short* __restrict__ yg) {
  __shared__ unsigned short ls[64][130];
  __shared__ int ridx[64];
  const int t = threadIdx.x;
  const int m0 = blockIdx.x * 64;
  if (t < 64) ridx[t] = r_index[m0 + t];
  __syncthreads();
  for (int it = 0; it < 32; ++it) {
    int idx = it * 256 + t;
    int ml = idx >> 7, b = idx & 127;
    ls[ml][b] = ut[(size_t)ridx[ml] * 128 + b];
  }
  __syncthreads();
  int b = t >> 1, half = t & 1;
#pragma unroll
  for (int c = 0; c < 4; ++c) {
    usx8 v;
#pragma unroll
    for (int e = 0; e < 8; ++e) v[e] = ls[half * 32 + c * 8 + e][b];
    *(usx8*)(yg + (size_t)b * 16384 + m0 + half * 32 + c * 8) = v;
  }
}

// ---------------------------------------------------------------------------
// GEMM v2' (R9 gemm2 + As pitch 64 w/ XOR chunk swizzle): grid (8,100),
// BK=64, bf16 partial.  LDS: As 2x128x64 (32KB) + Bs 2x64x72 (18.4KB) = 50KB
// -> 3 blocks/CU.
// ---------------------------------------------------------------------------
#define G2_KC 8
#define G2_STEPS 32
#define G2_PITCHB 72

__global__ __launch_bounds__(256) void k_gemm2(const unsigned short* __restrict__ yg,
                                               const float* __restrict__ cart,
                                               unsigned short* __restrict__ partial) {
  __shared__ unsigned short As[2][128][64];
  __shared__ unsigned short Bs[2][64][G2_PITCHB];
  const int t = threadIdx.x;
  const int lane = t & 63, w = t >> 6;
  const int kc = blockIdx.x;
  const int c0 = blockIdx.y * 64;
  const int k0 = kc * 2048;

  fx4 acc[2][4];
#pragma unroll
  for (int i = 0; i < 2; ++i)
#pragma unroll
    for (int j = 0; j < 4; ++j) acc[i][j] = (fx4)0.f;

  auto ldA = [&](int rep, int kpos) -> usx8 {
    int c = t + rep * 256;
    return *(const usx8*)(yg + (size_t)(c >> 3) * 16384 + kpos + (c & 7) * 8);
  };
  auto stA = [&](int buf, int rep, usx8 v) {
    int c = t + rep * 256;
    int row = c >> 3;
    int sw = (c & 7) ^ (row & 7);            // XOR chunk swizzle
    *(usx8*)(&As[buf][row][sw * 8]) = v;
  };
  auto ldB = [&](int rep, int kpos, fx4* f0, fx4* f1) {
    int c = t + rep * 256;
    const float* p = cart + (size_t)(c0 + (c >> 3)) * 16384 + kpos + (c & 7) * 8;
    *f0 = *(const fx4*)p;
    *f1 = *(const fx4*)(p + 4);
  };
  auto stB = [&](int buf, int rep, fx4 f0, fx4 f1) {
    int c = t + rep * 256;
    usx8 v;
    v[0]=f2bf(f0[0]); v[1]=f2bf(f0[1]); v[2]=f2bf(f0[2]); v[3]=f2bf(f0[3]);
    v[4]=f2bf(f1[0]); v[5]=f2bf(f1[1]); v[6]=f2bf(f1[2]); v[7]=f2bf(f1[3]);
    *(usx8*)(&Bs[buf][c >> 3][(c & 7) * 8]) = v;
  };

  {
    usx8 a0 = ldA(0, k0), a1 = ldA(1, k0), a2 = ldA(2, k0), a3 = ldA(3, k0);
    fx4 b00, b01, b10, b11;
    ldB(0, k0, &b00, &b01); ldB(1, k0, &b10, &b11);
    stA(0, 0, a0); stA(0, 1, a1); stA(0, 2, a2); stA(0, 3, a3);
    stB(0, 0, b00, b01); stB(0, 1, b10, b11);
  }
  __syncthreads();

  for (int s = 0; s < G2_STEPS; ++s) {
    const int cur = s & 1;
    usx8 av[4]; fx4 b00, b01, b10, b11;
    const bool pf = (s + 1 < G2_STEPS);
    if (pf) {
      int kpos = k0 + (s + 1) * 64;
      av[0] = ldA(0, kpos); av[1] = ldA(1, kpos);
      av[2] = ldA(2, kpos); av[3] = ldA(3, kpos);
      ldB(0, kpos, &b00, &b01); ldB(1, kpos, &b10, &b11);
    }
    sx8 af[2][2], bf[4][2];
#pragma unroll
    for (int mi = 0; mi < 2; ++mi)
#pragma unroll
      for (int kk = 0; kk < 2; ++kk) {
        int row = w * 32 + mi * 16 + (lane & 15);
        int ch = (kk * 4 + (lane >> 4)) ^ (row & 7);   // swizzled read
        af[mi][kk] = *(const sx8*)(&As[cur][row][ch * 8]);
      }
#pragma unroll
    for (int ni = 0; ni < 4; ++ni)
#pragma unroll
      for (int kk = 0; kk < 2; ++kk)
        bf[ni][kk] = *(const sx8*)(&Bs[cur][ni * 16 + (lane & 15)][kk * 32 + (lane >> 4) * 8]);
#pragma unroll
    for (int kk = 0; kk < 2; ++kk)
#pragma unroll
      for (int mi = 0; mi < 2; ++mi)
#pragma unroll
        for (int ni = 0; ni < 4; ++ni)
          acc[mi][ni] = __builtin_amdgcn_mfma_f32_16x16x32_bf16(af[mi][kk], bf[ni][kk], acc[mi][ni], 0, 0, 0);
    if (pf) {
      stA(cur ^ 1, 0, av[0]); stA(cur ^ 1, 1, av[1]);
      stA(cur ^ 1, 2, av[2]); stA(cur ^ 1, 3, av[3]);
      stB(cur ^ 1, 0, b00, b01); stB(cur ^ 1, 1, b10, b11);
    }
    __syncthreads();
  }

  // epilogue: partial[kc][b][c] bf16
#pragma unroll
  for (int mi = 0; mi < 2; ++mi) {
    int brow = w * 32 + mi * 16 + (lane >> 4) * 4;
#pragma unroll
    for (int ni = 0; ni < 4; ++ni) {
      int cc = c0 + ni * 16 + (lane & 15);
#pragma unroll
      for (int r = 0; r < 4; ++r)
        partial[((size_t)kc * 128 + brow + r) * 6400 + cc] = f2bf(acc[mi][ni][r]);
    }
  }
}

__global__ __launch_bounds__(256) void k_reduce2(const unsigned short* __restrict__ partial,
                                                 float* __restrict__ out) {
  int i = blockIdx.x * 256 + threadIdx.x;
  fx4 s = (fx4)0.f;
#pragma unroll
  for (int kc = 0; kc < G2_KC; ++kc) {
    usx4 v = *(const usx4*)(partial + (size_t)kc * 819200 + (size_t)i * 4);
    s[0] += bf2f(v[0]); s[1] += bf2f(v[1]); s[2] += bf2f(v[2]); s[3] += bf2f(v[3]);
  }
  *(fx4*)(out + (size_t)i * 4) = s;
}

// ---------------------------------------------------------------------------
extern "C" void kernel_launch(void* const* d_in, const int* in_sizes, int n_in,
                              void* d_out, int out_size, void* d_ws, size_t ws_size,
                              hipStream_t stream) {
  const float* x    = (const float*)d_in[0];
  const float* Vp   = (const float*)d_in[1];
  const float* Hp   = (const float*)d_in[2];
  const float* Mp   = (const float*)d_in[3];
  const float* Gp   = (const float*)d_in[4];
  const float* Up   = (const float*)d_in[5];
  const float* cart = (const float*)d_in[6];
  const int*   ridx = (const int*)d_in[7];
  float* out = (float*)d_out;
  unsigned short* hb = (unsigned short*)d_ws;

  const size_t PSZ = 4718592;
  f16* P0r = (f16*)(hb);
  f16* P0i = (f16*)(hb + PSZ);
  f16* P1r = (f16*)(hb + 2 * PSZ);
  f16* P1i = (f16*)(hb + 3 * PSZ);
  f16* xtr = (f16*)(hb + 4 * PSZ);
  f16* xti = (f16*)(hb + 4 * PSZ + 2097152);
  unsigned short* ut = hb + 4 * PSZ;
  unsigned short* yg = hb + 4 * PSZ + 2097152;
  unsigned short* partial = hb;

  const size_t HSZ = 8 * 32 * 36;

  k_transpose<<<dim3(128, 4), 256, 0, stream>>>(x, xtr, xti);
  k_vh<<<dim3(32, 32), 512, 0, stream>>>(xtr, xti, P0r, P0i, Vp, Hp + 0 * HSZ);
  k_hg<1><<<dim3(32, 32), 512, 0, stream>>>(P0r, P0i, P1r, P1i, Hp + 1 * HSZ);  // perm(l=4)
  k_hg<2><<<dim3(32, 32), 512, 0, stream>>>(P1r, P1i, P0r, P0i, Hp + 2 * HSZ);  // perm(l=3)
  k_mg<<<dim3(32, 32), 512, 0, stream>>>(P0r, P0i, P1r, P1i, Mp, Gp + 0 * HSZ); // switch+M123+G1
  k_hg<4><<<dim3(32, 32), 512, 0, stream>>>(P1r, P1i, P0r, P0i, Gp + 1 * HSZ);  // perm(l=2)
  k_hg<5><<<dim3(32, 32), 512, 0, stream>>>(P0r, P0i, P1r, P1i, Gp + 2 * HSZ);  // perm(l=1)
  k_u<<<dim3(64, 64), 128, 0, stream>>>(P1r, P1i, ut, Up);                      // perm(l=0) inside
  k_gather<<<dim3(256), 256, 0, stream>>>(ut, ridx, yg);
  k_gemm2<<<dim3(G2_KC, 100), 256, 0, stream>>>(yg, cart, partial);
  k_reduce2<<<dim3(800), 256, 0, stream>>>(partial, out);
  (void)in_sizes; (void)n_in; (void)out_size; (void)ws_size;
}

// Round 14
// 301.275 us; speedup vs baseline: 1.0717x; 1.0161x over previous
//
#include <hip/hip_runtime.h>

// ---------------------------------------------------------------------------
// equinet F* pipeline on MI355X.
// R14: best-known config = R9 exact (butterfly 512-thr 4-group term-split,
// gemm2 dual-LDS BK=64) + ONE change: k_u coarsened from 4096x128 to
// 1024x512 (4 U-units per block, one per 128-thread group).
// Ledger: all gemm2 mods regressed (R11 +8, R12 +23, R13 +6); all butterfly
// mods since R9 regressed (R10 MFMA +42). This is the measured optimum.
// ---------------------------------------------------------------------------

typedef _Float16 f16;
typedef __attribute__((ext_vector_type(8))) short sx8;
typedef __attribute__((ext_vector_type(4))) float fx4;
typedef __attribute__((ext_vector_type(8))) unsigned short usx8;
typedef __attribute__((ext_vector_type(4))) unsigned short usx4;

__device__ __forceinline__ unsigned short f2bf(float f) {
  unsigned u = __builtin_bit_cast(unsigned, f);
  u = (u + 0x7FFFu + ((u >> 16) & 1u)) >> 16;
  return (unsigned short)u;
}
__device__ __forceinline__ float bf2f(unsigned short h) {
  return __builtin_bit_cast(float, ((unsigned)h) << 16);
}

template<int ID>
__device__ __forceinline__ int rp_apply(int k) {
  if constexpr (ID == 0) { return k; }
  else if constexpr (ID == 3) { return (k & 7) * 8 + (k >> 3); }
  else {
    constexpr int l = (ID == 1) ? 4 : (ID == 2) ? 3 : (ID == 4) ? 2 : (ID == 5) ? 1 : 0;
    constexpr int d = 1 << (5 - l);
    constexpr int m2 = 2 * d;
    int g = k / m2, r = k % m2;
    return g * m2 + (r & 1) * d + (r >> 1);
  }
}

__device__ __forceinline__ void term_decode(int t, int& lm, int& rm,
                                            bool& useXi, bool& toYi) {
  lm = (t < 2) ? t : (t < 4) ? (t + 4) : (t - 2);
  rm = (t >= 2 && t <= 5) ? (lm ^ 1) : lm;
  useXi = (t >= 4);
  toYi = (t >> 1) & 1;
}

#define SMEM_BYTES 36864

// ---------------------------------------------------------------------------
// Phase B helper (R9): one 6x6-block complex layer, terms split over 4 groups.
// ---------------------------------------------------------------------------
__device__ __forceinline__ void layer6(int g, int b, int P, int Q,
                                       const float* __restrict__ wp,
                                       const f16* ldsX, float* Y0, float* Y1,
                                       f16* __restrict__ yr,
                                       f16* __restrict__ yi) {
  int lm0, rm0, lm1, rm1;
  switch (g) {
    case 0:  lm0 = 0; rm0 = 0; lm1 = 1; rm1 = 1; break;
    case 1:  lm0 = 6; rm0 = 7; lm1 = 7; rm1 = 6; break;
    case 2:  lm0 = 2; rm0 = 3; lm1 = 3; rm1 = 2; break;
    default: lm0 = 4; rm0 = 4; lm1 = 5; rm1 = 5; break;
  }
  const int xbase = (g & 2) ? 36 : 0;
  float X[36], Y[36];
#pragma unroll
  for (int k = 0; k < 36; ++k) X[k] = (float)ldsX[(xbase + k) * 128 + b];
#pragma unroll
  for (int k = 0; k < 36; ++k) Y[k] = 0.f;

  for (int tt = 0; tt < 2; ++tt) {
    const int lm = tt ? lm1 : lm0;
    const int rm = tt ? rm1 : rm0;
    const float* Lw = wp + ((size_t)lm * 32 + P) * 36;
    const float* Rw = wp + ((size_t)rm * 32 + Q) * 36;
#pragma unroll
    for (int i = 0; i < 6; ++i) {
      float tk[6] = {0.f, 0.f, 0.f, 0.f, 0.f, 0.f};
#pragma unroll
      for (int j = 0; j < 6; ++j) {
        float xv = X[i * 6 + j];
#pragma unroll
        for (int k = 0; k < 6; ++k) tk[k] += xv * Rw[j * 6 + k];
      }
#pragma unroll
      for (int o = 0; o < 6; ++o) {
        float lv = Lw[i * 6 + o];
#pragma unroll
        for (int k = 0; k < 6; ++k) Y[o * 6 + k] += lv * tk[k];
      }
    }
  }
  __syncthreads();
  if (g == 2) {
#pragma unroll
    for (int k = 0; k < 36; ++k) Y0[k * 128 + b] = Y[k];
  } else if (g == 3) {
#pragma unroll
    for (int k = 0; k < 36; ++k) Y1[k * 128 + b] = Y[k];
  }
  __syncthreads();
  if (g == 0) {
#pragma unroll
    for (int k = 0; k < 36; ++k) {
      float v = Y[k] + Y0[k * 128 + b];
      yr[((size_t)((P * 6 + k / 6) * 192 + Q * 6 + k % 6)) * 128 + b] = (f16)v;
    }
  } else if (g == 1) {
#pragma unroll
    for (int k = 0; k < 36; ++k) {
      float v = Y[k] + Y1[k * 128 + b];
      yi[((size_t)((P * 6 + k / 6) * 192 + Q * 6 + k % 6)) * 128 + b] = (f16)v;
    }
  }
}

// ---------------------------------------------------------------------------
// Transpose x (B,128,128,2) fp32 -> xtr/xti (16384, 128) fp16
// ---------------------------------------------------------------------------
__global__ __launch_bounds__(256) void k_transpose(const float* __restrict__ x,
                                                   f16* __restrict__ xtr,
                                                   f16* __restrict__ xti) {
  __shared__ float ls[2][32][129];
  const int t = threadIdx.x;
  const int u = blockIdx.x;
  const int v0 = blockIdx.y * 32;
  for (int it = 0; it < 32; ++it) {
    int b = it * 4 + (t >> 6);
    int r = t & 63;
    int v = r >> 1, ch = r & 1;
    ls[ch][v][b] = x[(((size_t)b * 128 + u) * 128 + (v0 + v)) * 2 + ch];
  }
  __syncthreads();
  for (int it = 0; it < 32; ++it) {
    int idx = it * 256 + t;
    int ch = idx >> 12;
    int v = (idx >> 7) & 31;
    int b = idx & 127;
    f16* dst = ch ? xti : xtr;
    dst[((size_t)(u * 128 + v0 + v)) * 128 + b] = (f16)ls[ch][v][b];
  }
}

// ---------------------------------------------------------------------------
// V + H1 fused (R9).
// ---------------------------------------------------------------------------
__global__ __launch_bounds__(512, 4) void k_vh(const f16* __restrict__ xtr,
                                               const f16* __restrict__ xti,
                                               f16* __restrict__ yr,
                                               f16* __restrict__ yi,
                                               const float* __restrict__ vp,
                                               const float* __restrict__ hp) {
  __shared__ __align__(16) char smem[SMEM_BYTES];
  f16* ldsX = (f16*)smem;
  float* Y0 = (float*)smem;
  float* Y1 = (float*)(smem + 18432);
  const int t = threadIdx.x;
  const int P = blockIdx.x, Q = blockIdx.y;
  const int g = __builtin_amdgcn_readfirstlane(t >> 7);
  const int b = t & 127;

  const int pp = g >> 1, qq = g & 1;
  const int p = 2 * P + pp, q = 2 * Q + qq;
  float Xr[4], Xi[4];
#pragma unroll
  for (int i = 0; i < 2; ++i)
#pragma unroll
    for (int j = 0; j < 2; ++j) {
      size_t off = ((size_t)((4 * P + 2 * pp + i) * 128 + (4 * Q + 2 * qq + j))) * 128 + b;
      Xr[i * 2 + j] = (float)xtr[off];
      Xi[i * 2 + j] = (float)xti[off];
    }
  float Ar[9], Ai[9];
#pragma unroll
  for (int k = 0; k < 9; ++k) { Ar[k] = 0.f; Ai[k] = 0.f; }
  for (int tt = 0; tt < 8; ++tt) {
    int lm, rm; bool useXi, toYi;
    term_decode(tt, lm, rm, useXi, toYi);
    const float* Lw = vp + ((size_t)lm * 64 + p) * 6;
    const float* Rw = vp + ((size_t)rm * 64 + q) * 6;
#pragma unroll
    for (int i = 0; i < 2; ++i) {
      float x0, x1;
      if (useXi) { x0 = Xi[i * 2 + 0]; x1 = Xi[i * 2 + 1]; }
      else       { x0 = Xr[i * 2 + 0]; x1 = Xr[i * 2 + 1]; }
      float t0 = x0 * Rw[0] + x1 * Rw[3];
      float t1 = x0 * Rw[1] + x1 * Rw[4];
      float t2 = x0 * Rw[2] + x1 * Rw[5];
      if (toYi) {
#pragma unroll
        for (int o = 0; o < 3; ++o) {
          float lv = Lw[i * 3 + o];
          Ai[o*3+0] += lv * t0; Ai[o*3+1] += lv * t1; Ai[o*3+2] += lv * t2;
        }
      } else {
#pragma unroll
        for (int o = 0; o < 3; ++o) {
          float lv = Lw[i * 3 + o];
          Ar[o*3+0] += lv * t0; Ar[o*3+1] += lv * t1; Ar[o*3+2] += lv * t2;
        }
      }
    }
  }
#pragma unroll
  for (int o = 0; o < 3; ++o)
#pragma unroll
    for (int k = 0; k < 3; ++k) {
      int ch = (3 * pp + o) * 6 + (3 * qq + k);
      ldsX[ch * 128 + b] = (f16)Ar[o * 3 + k];
      ldsX[(36 + ch) * 128 + b] = (f16)Ai[o * 3 + k];
    }
  __syncthreads();
  layer6(g, b, P, Q, hp, ldsX, Y0, Y1, yr, yi);
}

// ---------------------------------------------------------------------------
// H/G layer (R9): staged copy + term-split.
// ---------------------------------------------------------------------------
template<int PERM>
__global__ __launch_bounds__(512, 4) void k_hg(const f16* __restrict__ xr,
                                               const f16* __restrict__ xi,
                                               f16* __restrict__ yr,
                                               f16* __restrict__ yi,
                                               const float* __restrict__ wp) {
  __shared__ __align__(16) char smem[SMEM_BYTES];
  f16* ldsX = (f16*)smem;
  float* Y0 = (float*)smem;
  float* Y1 = (float*)(smem + 18432);
  const int t = threadIdx.x;
  const int P = blockIdx.x, Q = blockIdx.y;

  for (int r = 0; r < 3; ++r) {
    int idx = t + r * 512;
    if (idx < 1152) {
      int c = idx >> 4, o8 = (idx & 15) * 8;
      int cc = (c < 36) ? c : c - 36;
      int I = cc / 6, J = cc % 6;
      int grow = rp_apply<PERM>(2 * P + I / 3) * 3 + I % 3;
      int gcol = rp_apply<PERM>(2 * Q + J / 3) * 3 + J % 3;
      const f16* src = (c < 36) ? xr : xi;
      usx8 v = *(const usx8*)(src + ((size_t)(grow * 192 + gcol)) * 128 + o8);
      *(usx8*)(ldsX + c * 128 + o8) = v;
    }
  }
  __syncthreads();
  const int g = __builtin_amdgcn_readfirstlane(t >> 7);
  const int b = t & 127;
  layer6(g, b, P, Q, wp, ldsX, Y0, Y1, yr, yi);
}

// ---------------------------------------------------------------------------
// switch + M1..M3 + G1 (R9).
// ---------------------------------------------------------------------------
__global__ __launch_bounds__(512, 4) void k_mg(const f16* __restrict__ xr,
                                               const f16* __restrict__ xi,
                                               f16* __restrict__ yr,
                                               f16* __restrict__ yi,
                                               const float* __restrict__ mp,
                                               const float* __restrict__ gp) {
  __shared__ __align__(16) char smem[SMEM_BYTES];
  f16* ldsX = (f16*)smem;
  float* Y0 = (float*)smem;
  float* Y1 = (float*)(smem + 18432);
  const int t = threadIdx.x;
  const int P = blockIdx.x, Q = blockIdx.y;
  const int g = __builtin_amdgcn_readfirstlane(t >> 7);
  const int b = t & 127;

  const int aa = g >> 1, bb = g & 1;
  const int p = 2 * P + aa, q = 2 * Q + bb;
  const int prow = rp_apply<3>(p) * 3, pcol = rp_apply<3>(q) * 3;
  float Xr[9], Xi[9];
#pragma unroll
  for (int i = 0; i < 3; ++i)
#pragma unroll
    for (int j = 0; j < 3; ++j) {
      size_t off = ((size_t)((prow + i) * 192 + (pcol + j))) * 128 + b;
      Xr[i * 3 + j] = (float)xr[off];
      Xi[i * 3 + j] = (float)xi[off];
    }
  for (int lk = 0; lk < 3; ++lk) {
    const float* wp = mp + (size_t)lk * (8 * 64 * 9);
    float Yr9[9], Yi9[9];
#pragma unroll
    for (int k = 0; k < 9; ++k) { Yr9[k] = Xr[k]; Yi9[k] = Xi[k]; }
    for (int tt = 0; tt < 8; ++tt) {
      int lm, rm; bool useXi, toYi;
      term_decode(tt, lm, rm, useXi, toYi);
      const float* Lw = wp + ((size_t)lm * 64 + p) * 9;
      const float* Rw = wp + ((size_t)rm * 64 + q) * 9;
#pragma unroll
      for (int i = 0; i < 3; ++i) {
        float x0, x1, x2;
        if (useXi) { x0 = Xi[i*3+0]; x1 = Xi[i*3+1]; x2 = Xi[i*3+2]; }
        else       { x0 = Xr[i*3+0]; x1 = Xr[i*3+1]; x2 = Xr[i*3+2]; }
        float t0 = x0 * Rw[0] + x1 * Rw[3] + x2 * Rw[6];
        float t1 = x0 * Rw[1] + x1 * Rw[4] + x2 * Rw[7];
        float t2 = x0 * Rw[2] + x1 * Rw[5] + x2 * Rw[8];
        if (toYi) {
#pragma unroll
          for (int o = 0; o < 3; ++o) {
            float lv = Lw[i * 3 + o];
            Yi9[o*3+0] += lv * t0; Yi9[o*3+1] += lv * t1; Yi9[o*3+2] += lv * t2;
          }
        } else {
#pragma unroll
          for (int o = 0; o < 3; ++o) {
            float lv = Lw[i * 3 + o];
            Yr9[o*3+0] += lv * t0; Yr9[o*3+1] += lv * t1; Yr9[o*3+2] += lv * t2;
          }
        }
      }
    }
#pragma unroll
    for (int k = 0; k < 9; ++k) { Xr[k] = Yr9[k]; Xi[k] = Yi9[k]; }
  }
#pragma unroll
  for (int i = 0; i < 3; ++i)
#pragma unroll
    for (int j = 0; j < 3; ++j) {
      int ch = (3 * aa + i) * 6 + (3 * bb + j);
      ldsX[ch * 128 + b] = (f16)Xr[i * 3 + j];
      ldsX[(36 + ch) * 128 + b] = (f16)Xi[i * 3 + j];
    }
  __syncthreads();
  layer6(g, b, P, Q, gp, ldsX, Y0, Y1, yr, yi);
}

// ---------------------------------------------------------------------------
// U layer, coarsened: 512 threads = 4 U-units (one per 128-thread group).
// perm(l=0) on read. Up:(8,64,3,2).  Grid (32,32) covers 64x64 units.
// ---------------------------------------------------------------------------
__global__ __launch_bounds__(512, 4) void k_u2(const f16* __restrict__ xr,
                                               const f16* __restrict__ xi,
                                               unsigned short* __restrict__ ut,
                                               const float* __restrict__ wp) {
  const int t = threadIdx.x;
  const int g = __builtin_amdgcn_readfirstlane(t >> 7);
  const int b = t & 127;
  const int p = 2 * blockIdx.x + (g >> 1);
  const int q = 2 * blockIdx.y + (g & 1);
  int rrow[3], rcol[3];
#pragma unroll
  for (int i = 0; i < 3; ++i) {
    rrow[i] = rp_apply<6>(p) * 3 + i;
    rcol[i] = rp_apply<6>(q) * 3 + i;
  }
  float X[9], Y[4] = {0.f, 0.f, 0.f, 0.f};
  auto loadX = [&](const f16* src) {
#pragma unroll
    for (int i = 0; i < 3; ++i)
#pragma unroll
      for (int j = 0; j < 3; ++j)
        X[i * 3 + j] = (float)src[((size_t)(rrow[i] * 192 + rcol[j])) * 128 + b];
  };
  auto term = [&](int lm, int rm) {
    const float* Lw = wp + ((size_t)lm * 64 + p) * 6;
    const float* Rw = wp + ((size_t)rm * 64 + q) * 6;
#pragma unroll
    for (int i = 0; i < 3; ++i) {
      float t0 = X[i*3+0] * Rw[0] + X[i*3+1] * Rw[2] + X[i*3+2] * Rw[4];
      float t1 = X[i*3+0] * Rw[1] + X[i*3+1] * Rw[3] + X[i*3+2] * Rw[5];
      Y[0] += Lw[i*2+0] * t0; Y[1] += Lw[i*2+0] * t1;
      Y[2] += Lw[i*2+1] * t0; Y[3] += Lw[i*2+1] * t1;
    }
  };
  loadX(xr); term(0, 0); term(3, 3);
  loadX(xi); term(4, 5); term(7, 6);
#pragma unroll
  for (int o = 0; o < 2; ++o)
#pragma unroll
    for (int k = 0; k < 2; ++k)
      ut[((size_t)((p * 2 + o) * 128 + (q * 2 + k))) * 128 + b] = f2bf(Y[o * 2 + k]);
}

// ---------------------------------------------------------------------------
// Gather + transpose (R9)
// ---------------------------------------------------------------------------
__global__ __launch_bounds__(256) void k_gather(const unsigned short* __restrict__ ut,
                                                const int* __restrict__ r_index,
                                                unsigned short* __restrict__ yg) {
  __shared__ unsigned short ls[64][130];
  __shared__ int ridx[64];
  const int t = threadIdx.x;
  const int m0 = blockIdx.x * 64;
  if (t < 64) ridx[t] = r_index[m0 + t];
  __syncthreads();
  for (int it = 0; it < 32; ++it) {
    int idx = it * 256 + t;
    int ml = idx >> 7, b = idx & 127;
    ls[ml][b] = ut[(size_t)ridx[ml] * 128 + b];
  }
  __syncthreads();
  int b = t >> 1, half = t & 1;
#pragma unroll
  for (int c = 0; c < 4; ++c) {
    usx8 v;
#pragma unroll
    for (int e = 0; e < 8; ++e) v[e] = ls[half * 32 + c * 8 + e][b];
    *(usx8*)(yg + (size_t)b * 16384 + m0 + half * 32 + c * 8) = v;
  }
}

// ---------------------------------------------------------------------------
// GEMM v2 (R9 exact): grid (8,100), BK=64, dual-LDS pitch-72, bf16 partial.
// ---------------------------------------------------------------------------
#define G2_KC 8
#define G2_STEPS 32
#define G2_PITCH 72

__global__ __launch_bounds__(256) void k_gemm2(const unsigned short* __restrict__ yg,
                                               const float* __restrict__ cart,
                                               unsigned short* __restrict__ partial) {
  __shared__ unsigned short As[2][128][G2_PITCH];
  __shared__ unsigned short Bs[2][64][G2_PITCH];
  const int t = threadIdx.x;
  const int lane = t & 63, w = t >> 6;
  const int kc = blockIdx.x;
  const int c0 = blockIdx.y * 64;
  const int k0 = kc * 2048;

  fx4 acc[2][4];
#pragma unroll
  for (int i = 0; i < 2; ++i)
#pragma unroll
    for (int j = 0; j < 4; ++j) acc[i][j] = (fx4)0.f;

  auto ldA = [&](int rep, int kpos) -> usx8 {
    int c = t + rep * 256;
    return *(const usx8*)(yg + (size_t)(c >> 3) * 16384 + kpos + (c & 7) * 8);
  };
  auto stA = [&](int buf, int rep, usx8 v) {
    int c = t + rep * 256;
    *(usx8*)(&As[buf][c >> 3][(c & 7) * 8]) = v;
  };
  auto ldB = [&](int rep, int kpos, fx4* f0, fx4* f1) {
    int c = t + rep * 256;
    const float* p = cart + (size_t)(c0 + (c >> 3)) * 16384 + kpos + (c & 7) * 8;
    *f0 = *(const fx4*)p;
    *f1 = *(const fx4*)(p + 4);
  };
  auto stB = [&](int buf, int rep, fx4 f0, fx4 f1) {
    int c = t + rep * 256;
    usx8 v;
    v[0]=f2bf(f0[0]); v[1]=f2bf(f0[1]); v[2]=f2bf(f0[2]); v[3]=f2bf(f0[3]);
    v[4]=f2bf(f1[0]); v[5]=f2bf(f1[1]); v[6]=f2bf(f1[2]); v[7]=f2bf(f1[3]);
    *(usx8*)(&Bs[buf][c >> 3][(c & 7) * 8]) = v;
  };

  {
    usx8 a0 = ldA(0, k0), a1 = ldA(1, k0), a2 = ldA(2, k0), a3 = ldA(3, k0);
    fx4 b00, b01, b10, b11;
    ldB(0, k0, &b00, &b01); ldB(1, k0, &b10, &b11);
    stA(0, 0, a0); stA(0, 1, a1); stA(0, 2, a2); stA(0, 3, a3);
    stB(0, 0, b00, b01); stB(0, 1, b10, b11);
  }
  __syncthreads();

  for (int s = 0; s < G2_STEPS; ++s) {
    const int cur = s & 1;
    usx8 av[4]; fx4 b00, b01, b10, b11;
    const bool pf = (s + 1 < G2_STEPS);
    if (pf) {
      int kpos = k0 + (s + 1) * 64;
      av[0] = ldA(0, kpos); av[1] = ldA(1, kpos);
      av[2] = ldA(2, kpos); av[3] = ldA(3, kpos);
      ldB(0, kpos, &b00, &b01); ldB(1, kpos, &b10, &b11);
    }
    sx8 af[2][2], bf[4][2];
#pragma unroll
    for (int mi = 0; mi < 2; ++mi)
#pragma unroll
      for (int kk = 0; kk < 2; ++kk)
        af[mi][kk] = *(const sx8*)(&As[cur][w * 32 + mi * 16 + (lane & 15)][kk * 32 + (lane >> 4) * 8]);
#pragma unroll
    for (int ni = 0; ni < 4; ++ni)
#pragma unroll
      for (int kk = 0; kk < 2; ++kk)
        bf[ni][kk] = *(const sx8*)(&Bs[cur][ni * 16 + (lane & 15)][kk * 32 + (lane >> 4) * 8]);
#pragma unroll
    for (int kk = 0; kk < 2; ++kk)
#pragma unroll
      for (int mi = 0; mi < 2; ++mi)
#pragma unroll
        for (int ni = 0; ni < 4; ++ni)
          acc[mi][ni] = __builtin_amdgcn_mfma_f32_16x16x32_bf16(af[mi][kk], bf[ni][kk], acc[mi][ni], 0, 0, 0);
    if (pf) {
      stA(cur ^ 1, 0, av[0]); stA(cur ^ 1, 1, av[1]);
      stA(cur ^ 1, 2, av[2]); stA(cur ^ 1, 3, av[3]);
      stB(cur ^ 1, 0, b00, b01); stB(cur ^ 1, 1, b10, b11);
    }
    __syncthreads();
  }

#pragma unroll
  for (int mi = 0; mi < 2; ++mi) {
    int brow = w * 32 + mi * 16 + (lane >> 4) * 4;
#pragma unroll
    for (int ni = 0; ni < 4; ++ni) {
      int cc = c0 + ni * 16 + (lane & 15);
#pragma unroll
      for (int r = 0; r < 4; ++r)
        partial[((size_t)kc * 128 + brow + r) * 6400 + cc] = f2bf(acc[mi][ni][r]);
    }
  }
}

__global__ __launch_bounds__(256) void k_reduce2(const unsigned short* __restrict__ partial,
                                                 float* __restrict__ out) {
  int i = blockIdx.x * 256 + threadIdx.x;
  fx4 s = (fx4)0.f;
#pragma unroll
  for (int kc = 0; kc < G2_KC; ++kc) {
    usx4 v = *(const usx4*)(partial + (size_t)kc * 819200 + (size_t)i * 4);
    s[0] += bf2f(v[0]); s[1] += bf2f(v[1]); s[2] += bf2f(v[2]); s[3] += bf2f(v[3]);
  }
  *(fx4*)(out + (size_t)i * 4) = s;
}

// ---------------------------------------------------------------------------
extern "C" void kernel_launch(void* const* d_in, const int* in_sizes, int n_in,
                              void* d_out, int out_size, void* d_ws, size_t ws_size,
                              hipStream_t stream) {
  const float* x    = (const float*)d_in[0];
  const float* Vp   = (const float*)d_in[1];
  const float* Hp   = (const float*)d_in[2];
  const float* Mp   = (const float*)d_in[3];
  const float* Gp   = (const float*)d_in[4];
  const float* Up   = (const float*)d_in[5];
  const float* cart = (const float*)d_in[6];
  const int*   ridx = (const int*)d_in[7];
  float* out = (float*)d_out;
  unsigned short* hb = (unsigned short*)d_ws;

  const size_t PSZ = 4718592;
  f16* P0r = (f16*)(hb);
  f16* P0i = (f16*)(hb + PSZ);
  f16* P1r = (f16*)(hb + 2 * PSZ);
  f16* P1i = (f16*)(hb + 3 * PSZ);
  f16* xtr = (f16*)(hb + 4 * PSZ);
  f16* xti = (f16*)(hb + 4 * PSZ + 2097152);
  unsigned short* ut = hb + 4 * PSZ;
  unsigned short* yg = hb + 4 * PSZ + 2097152;
  unsigned short* partial = hb;

  const size_t HSZ = 8 * 32 * 36;

  k_transpose<<<dim3(128, 4), 256, 0, stream>>>(x, xtr, xti);
  k_vh<<<dim3(32, 32), 512, 0, stream>>>(xtr, xti, P0r, P0i, Vp, Hp + 0 * HSZ);
  k_hg<1><<<dim3(32, 32), 512, 0, stream>>>(P0r, P0i, P1r, P1i, Hp + 1 * HSZ);  // perm(l=4)
  k_hg<2><<<dim3(32, 32), 512, 0, stream>>>(P1r, P1i, P0r, P0i, Hp + 2 * HSZ);  // perm(l=3)
  k_mg<<<dim3(32, 32), 512, 0, stream>>>(P0r, P0i, P1r, P1i, Mp, Gp + 0 * HSZ); // switch+M123+G1
  k_hg<4><<<dim3(32, 32), 512, 0, stream>>>(P1r, P1i, P0r, P0i, Gp + 1 * HSZ);  // perm(l=2)
  k_hg<5><<<dim3(32, 32), 512, 0, stream>>>(P0r, P0i, P1r, P1i, Gp + 2 * HSZ);  // perm(l=1)
  k_u2<<<dim3(32, 32), 512, 0, stream>>>(P1r, P1i, ut, Up);                     // perm(l=0) inside
  k_gather<<<dim3(256), 256, 0, stream>>>(ut, ridx, yg);
  k_gemm2<<<dim3(G2_KC, 100), 256, 0, stream>>>(yg, cart, partial);
  k_reduce2<<<dim3(800), 256, 0, stream>>>(partial, out);
  (void)in_sizes; (void)n_in; (void)out_size; (void)ws_size;
}

// Round 15
// 296.828 us; speedup vs baseline: 1.0877x; 1.0150x over previous
//
#include <hip/hip_runtime.h>

// ---------------------------------------------------------------------------
// equinet F* pipeline on MI355X.
// R15: butterfly = R14 (R9 + coarsened k_u2). GEMM v5 = R9's gemm2 with
// ONE change: B triple-buffered depth-2 (store tile s+1 at step-top from regs
// loaded in step s-1 — aged a full step ~1000cy >= HBM latency; issue s+2).
// BK stays 64 (R12's regression was the doubled barrier count, not depth-2).
// A-path unchanged (L2-resident, depth-1 late-store covers ~200cy).
// LDS 36.9+27.6=64.5KB -> still 2 blocks/CU.
// ---------------------------------------------------------------------------

typedef _Float16 f16;
typedef __attribute__((ext_vector_type(8))) short sx8;
typedef __attribute__((ext_vector_type(4))) float fx4;
typedef __attribute__((ext_vector_type(8))) unsigned short usx8;
typedef __attribute__((ext_vector_type(4))) unsigned short usx4;

__device__ __forceinline__ unsigned short f2bf(float f) {
  unsigned u = __builtin_bit_cast(unsigned, f);
  u = (u + 0x7FFFu + ((u >> 16) & 1u)) >> 16;
  return (unsigned short)u;
}
__device__ __forceinline__ float bf2f(unsigned short h) {
  return __builtin_bit_cast(float, ((unsigned)h) << 16);
}

template<int ID>
__device__ __forceinline__ int rp_apply(int k) {
  if constexpr (ID == 0) { return k; }
  else if constexpr (ID == 3) { return (k & 7) * 8 + (k >> 3); }
  else {
    constexpr int l = (ID == 1) ? 4 : (ID == 2) ? 3 : (ID == 4) ? 2 : (ID == 5) ? 1 : 0;
    constexpr int d = 1 << (5 - l);
    constexpr int m2 = 2 * d;
    int g = k / m2, r = k % m2;
    return g * m2 + (r & 1) * d + (r >> 1);
  }
}

__device__ __forceinline__ void term_decode(int t, int& lm, int& rm,
                                            bool& useXi, bool& toYi) {
  lm = (t < 2) ? t : (t < 4) ? (t + 4) : (t - 2);
  rm = (t >= 2 && t <= 5) ? (lm ^ 1) : lm;
  useXi = (t >= 4);
  toYi = (t >> 1) & 1;
}

#define SMEM_BYTES 36864

// ---------------------------------------------------------------------------
// Phase B helper (R9): one 6x6-block complex layer, terms split over 4 groups.
// ---------------------------------------------------------------------------
__device__ __forceinline__ void layer6(int g, int b, int P, int Q,
                                       const float* __restrict__ wp,
                                       const f16* ldsX, float* Y0, float* Y1,
                                       f16* __restrict__ yr,
                                       f16* __restrict__ yi) {
  int lm0, rm0, lm1, rm1;
  switch (g) {
    case 0:  lm0 = 0; rm0 = 0; lm1 = 1; rm1 = 1; break;
    case 1:  lm0 = 6; rm0 = 7; lm1 = 7; rm1 = 6; break;
    case 2:  lm0 = 2; rm0 = 3; lm1 = 3; rm1 = 2; break;
    default: lm0 = 4; rm0 = 4; lm1 = 5; rm1 = 5; break;
  }
  const int xbase = (g & 2) ? 36 : 0;
  float X[36], Y[36];
#pragma unroll
  for (int k = 0; k < 36; ++k) X[k] = (float)ldsX[(xbase + k) * 128 + b];
#pragma unroll
  for (int k = 0; k < 36; ++k) Y[k] = 0.f;

  for (int tt = 0; tt < 2; ++tt) {
    const int lm = tt ? lm1 : lm0;
    const int rm = tt ? rm1 : rm0;
    const float* Lw = wp + ((size_t)lm * 32 + P) * 36;
    const float* Rw = wp + ((size_t)rm * 32 + Q) * 36;
#pragma unroll
    for (int i = 0; i < 6; ++i) {
      float tk[6] = {0.f, 0.f, 0.f, 0.f, 0.f, 0.f};
#pragma unroll
      for (int j = 0; j < 6; ++j) {
        float xv = X[i * 6 + j];
#pragma unroll
        for (int k = 0; k < 6; ++k) tk[k] += xv * Rw[j * 6 + k];
      }
#pragma unroll
      for (int o = 0; o < 6; ++o) {
        float lv = Lw[i * 6 + o];
#pragma unroll
        for (int k = 0; k < 6; ++k) Y[o * 6 + k] += lv * tk[k];
      }
    }
  }
  __syncthreads();
  if (g == 2) {
#pragma unroll
    for (int k = 0; k < 36; ++k) Y0[k * 128 + b] = Y[k];
  } else if (g == 3) {
#pragma unroll
    for (int k = 0; k < 36; ++k) Y1[k * 128 + b] = Y[k];
  }
  __syncthreads();
  if (g == 0) {
#pragma unroll
    for (int k = 0; k < 36; ++k) {
      float v = Y[k] + Y0[k * 128 + b];
      yr[((size_t)((P * 6 + k / 6) * 192 + Q * 6 + k % 6)) * 128 + b] = (f16)v;
    }
  } else if (g == 1) {
#pragma unroll
    for (int k = 0; k < 36; ++k) {
      float v = Y[k] + Y1[k * 128 + b];
      yi[((size_t)((P * 6 + k / 6) * 192 + Q * 6 + k % 6)) * 128 + b] = (f16)v;
    }
  }
}

// ---------------------------------------------------------------------------
// Transpose x (B,128,128,2) fp32 -> xtr/xti (16384, 128) fp16
// ---------------------------------------------------------------------------
__global__ __launch_bounds__(256) void k_transpose(const float* __restrict__ x,
                                                   f16* __restrict__ xtr,
                                                   f16* __restrict__ xti) {
  __shared__ float ls[2][32][129];
  const int t = threadIdx.x;
  const int u = blockIdx.x;
  const int v0 = blockIdx.y * 32;
  for (int it = 0; it < 32; ++it) {
    int b = it * 4 + (t >> 6);
    int r = t & 63;
    int v = r >> 1, ch = r & 1;
    ls[ch][v][b] = x[(((size_t)b * 128 + u) * 128 + (v0 + v)) * 2 + ch];
  }
  __syncthreads();
  for (int it = 0; it < 32; ++it) {
    int idx = it * 256 + t;
    int ch = idx >> 12;
    int v = (idx >> 7) & 31;
    int b = idx & 127;
    f16* dst = ch ? xti : xtr;
    dst[((size_t)(u * 128 + v0 + v)) * 128 + b] = (f16)ls[ch][v][b];
  }
}

// ---------------------------------------------------------------------------
// V + H1 fused (R9).
// ---------------------------------------------------------------------------
__global__ __launch_bounds__(512, 4) void k_vh(const f16* __restrict__ xtr,
                                               const f16* __restrict__ xti,
                                               f16* __restrict__ yr,
                                               f16* __restrict__ yi,
                                               const float* __restrict__ vp,
                                               const float* __restrict__ hp) {
  __shared__ __align__(16) char smem[SMEM_BYTES];
  f16* ldsX = (f16*)smem;
  float* Y0 = (float*)smem;
  float* Y1 = (float*)(smem + 18432);
  const int t = threadIdx.x;
  const int P = blockIdx.x, Q = blockIdx.y;
  const int g = __builtin_amdgcn_readfirstlane(t >> 7);
  const int b = t & 127;

  const int pp = g >> 1, qq = g & 1;
  const int p = 2 * P + pp, q = 2 * Q + qq;
  float Xr[4], Xi[4];
#pragma unroll
  for (int i = 0; i < 2; ++i)
#pragma unroll
    for (int j = 0; j < 2; ++j) {
      size_t off = ((size_t)((4 * P + 2 * pp + i) * 128 + (4 * Q + 2 * qq + j))) * 128 + b;
      Xr[i * 2 + j] = (float)xtr[off];
      Xi[i * 2 + j] = (float)xti[off];
    }
  float Ar[9], Ai[9];
#pragma unroll
  for (int k = 0; k < 9; ++k) { Ar[k] = 0.f; Ai[k] = 0.f; }
  for (int tt = 0; tt < 8; ++tt) {
    int lm, rm; bool useXi, toYi;
    term_decode(tt, lm, rm, useXi, toYi);
    const float* Lw = vp + ((size_t)lm * 64 + p) * 6;
    const float* Rw = vp + ((size_t)rm * 64 + q) * 6;
#pragma unroll
    for (int i = 0; i < 2; ++i) {
      float x0, x1;
      if (useXi) { x0 = Xi[i * 2 + 0]; x1 = Xi[i * 2 + 1]; }
      else       { x0 = Xr[i * 2 + 0]; x1 = Xr[i * 2 + 1]; }
      float t0 = x0 * Rw[0] + x1 * Rw[3];
      float t1 = x0 * Rw[1] + x1 * Rw[4];
      float t2 = x0 * Rw[2] + x1 * Rw[5];
      if (toYi) {
#pragma unroll
        for (int o = 0; o < 3; ++o) {
          float lv = Lw[i * 3 + o];
          Ai[o*3+0] += lv * t0; Ai[o*3+1] += lv * t1; Ai[o*3+2] += lv * t2;
        }
      } else {
#pragma unroll
        for (int o = 0; o < 3; ++o) {
          float lv = Lw[i * 3 + o];
          Ar[o*3+0] += lv * t0; Ar[o*3+1] += lv * t1; Ar[o*3+2] += lv * t2;
        }
      }
    }
  }
#pragma unroll
  for (int o = 0; o < 3; ++o)
#pragma unroll
    for (int k = 0; k < 3; ++k) {
      int ch = (3 * pp + o) * 6 + (3 * qq + k);
      ldsX[ch * 128 + b] = (f16)Ar[o * 3 + k];
      ldsX[(36 + ch) * 128 + b] = (f16)Ai[o * 3 + k];
    }
  __syncthreads();
  layer6(g, b, P, Q, hp, ldsX, Y0, Y1, yr, yi);
}

// ---------------------------------------------------------------------------
// H/G layer (R9): staged copy + term-split.
// ---------------------------------------------------------------------------
template<int PERM>
__global__ __launch_bounds__(512, 4) void k_hg(const f16* __restrict__ xr,
                                               const f16* __restrict__ xi,
                                               f16* __restrict__ yr,
                                               f16* __restrict__ yi,
                                               const float* __restrict__ wp) {
  __shared__ __align__(16) char smem[SMEM_BYTES];
  f16* ldsX = (f16*)smem;
  float* Y0 = (float*)smem;
  float* Y1 = (float*)(smem + 18432);
  const int t = threadIdx.x;
  const int P = blockIdx.x, Q = blockIdx.y;

  for (int r = 0; r < 3; ++r) {
    int idx = t + r * 512;
    if (idx < 1152) {
      int c = idx >> 4, o8 = (idx & 15) * 8;
      int cc = (c < 36) ? c : c - 36;
      int I = cc / 6, J = cc % 6;
      int grow = rp_apply<PERM>(2 * P + I / 3) * 3 + I % 3;
      int gcol = rp_apply<PERM>(2 * Q + J / 3) * 3 + J % 3;
      const f16* src = (c < 36) ? xr : xi;
      usx8 v = *(const usx8*)(src + ((size_t)(grow * 192 + gcol)) * 128 + o8);
      *(usx8*)(ldsX + c * 128 + o8) = v;
    }
  }
  __syncthreads();
  const int g = __builtin_amdgcn_readfirstlane(t >> 7);
  const int b = t & 127;
  layer6(g, b, P, Q, wp, ldsX, Y0, Y1, yr, yi);
}

// ---------------------------------------------------------------------------
// switch + M1..M3 + G1 (R9).
// ---------------------------------------------------------------------------
__global__ __launch_bounds__(512, 4) void k_mg(const f16* __restrict__ xr,
                                               const f16* __restrict__ xi,
                                               f16* __restrict__ yr,
                                               f16* __restrict__ yi,
                                               const float* __restrict__ mp,
                                               const float* __restrict__ gp) {
  __shared__ __align__(16) char smem[SMEM_BYTES];
  f16* ldsX = (f16*)smem;
  float* Y0 = (float*)smem;
  float* Y1 = (float*)(smem + 18432);
  const int t = threadIdx.x;
  const int P = blockIdx.x, Q = blockIdx.y;
  const int g = __builtin_amdgcn_readfirstlane(t >> 7);
  const int b = t & 127;

  const int aa = g >> 1, bb = g & 1;
  const int p = 2 * P + aa, q = 2 * Q + bb;
  const int prow = rp_apply<3>(p) * 3, pcol = rp_apply<3>(q) * 3;
  float Xr[9], Xi[9];
#pragma unroll
  for (int i = 0; i < 3; ++i)
#pragma unroll
    for (int j = 0; j < 3; ++j) {
      size_t off = ((size_t)((prow + i) * 192 + (pcol + j))) * 128 + b;
      Xr[i * 3 + j] = (float)xr[off];
      Xi[i * 3 + j] = (float)xi[off];
    }
  for (int lk = 0; lk < 3; ++lk) {
    const float* wp = mp + (size_t)lk * (8 * 64 * 9);
    float Yr9[9], Yi9[9];
#pragma unroll
    for (int k = 0; k < 9; ++k) { Yr9[k] = Xr[k]; Yi9[k] = Xi[k]; }
    for (int tt = 0; tt < 8; ++tt) {
      int lm, rm; bool useXi, toYi;
      term_decode(tt, lm, rm, useXi, toYi);
      const float* Lw = wp + ((size_t)lm * 64 + p) * 9;
      const float* Rw = wp + ((size_t)rm * 64 + q) * 9;
#pragma unroll
      for (int i = 0; i < 3; ++i) {
        float x0, x1, x2;
        if (useXi) { x0 = Xi[i*3+0]; x1 = Xi[i*3+1]; x2 = Xi[i*3+2]; }
        else       { x0 = Xr[i*3+0]; x1 = Xr[i*3+1]; x2 = Xr[i*3+2]; }
        float t0 = x0 * Rw[0] + x1 * Rw[3] + x2 * Rw[6];
        float t1 = x0 * Rw[1] + x1 * Rw[4] + x2 * Rw[7];
        float t2 = x0 * Rw[2] + x1 * Rw[5] + x2 * Rw[8];
        if (toYi) {
#pragma unroll
          for (int o = 0; o < 3; ++o) {
            float lv = Lw[i * 3 + o];
            Yi9[o*3+0] += lv * t0; Yi9[o*3+1] += lv * t1; Yi9[o*3+2] += lv * t2;
          }
        } else {
#pragma unroll
          for (int o = 0; o < 3; ++o) {
            float lv = Lw[i * 3 + o];
            Yr9[o*3+0] += lv * t0; Yr9[o*3+1] += lv * t1; Yr9[o*3+2] += lv * t2;
          }
        }
      }
    }
#pragma unroll
    for (int k = 0; k < 9; ++k) { Xr[k] = Yr9[k]; Xi[k] = Yi9[k]; }
  }
#pragma unroll
  for (int i = 0; i < 3; ++i)
#pragma unroll
    for (int j = 0; j < 3; ++j) {
      int ch = (3 * aa + i) * 6 + (3 * bb + j);
      ldsX[ch * 128 + b] = (f16)Xr[i * 3 + j];
      ldsX[(36 + ch) * 128 + b] = (f16)Xi[i * 3 + j];
    }
  __syncthreads();
  layer6(g, b, P, Q, gp, ldsX, Y0, Y1, yr, yi);
}

// ---------------------------------------------------------------------------
// U layer coarsened (R14). perm(l=0) on read. Up:(8,64,3,2)
// ---------------------------------------------------------------------------
__global__ __launch_bounds__(512, 4) void k_u2(const f16* __restrict__ xr,
                                               const f16* __restrict__ xi,
                                               unsigned short* __restrict__ ut,
                                               const float* __restrict__ wp) {
  const int t = threadIdx.x;
  const int g = __builtin_amdgcn_readfirstlane(t >> 7);
  const int b = t & 127;
  const int p = 2 * blockIdx.x + (g >> 1);
  const int q = 2 * blockIdx.y + (g & 1);
  int rrow[3], rcol[3];
#pragma unroll
  for (int i = 0; i < 3; ++i) {
    rrow[i] = rp_apply<6>(p) * 3 + i;
    rcol[i] = rp_apply<6>(q) * 3 + i;
  }
  float X[9], Y[4] = {0.f, 0.f, 0.f, 0.f};
  auto loadX = [&](const f16* src) {
#pragma unroll
    for (int i = 0; i < 3; ++i)
#pragma unroll
      for (int j = 0; j < 3; ++j)
        X[i * 3 + j] = (float)src[((size_t)(rrow[i] * 192 + rcol[j])) * 128 + b];
  };
  auto term = [&](int lm, int rm) {
    const float* Lw = wp + ((size_t)lm * 64 + p) * 6;
    const float* Rw = wp + ((size_t)rm * 64 + q) * 6;
#pragma unroll
    for (int i = 0; i < 3; ++i) {
      float t0 = X[i*3+0] * Rw[0] + X[i*3+1] * Rw[2] + X[i*3+2] * Rw[4];
      float t1 = X[i*3+0] * Rw[1] + X[i*3+1] * Rw[3] + X[i*3+2] * Rw[5];
      Y[0] += Lw[i*2+0] * t0; Y[1] += Lw[i*2+0] * t1;
      Y[2] += Lw[i*2+1] * t0; Y[3] += Lw[i*2+1] * t1;
    }
  };
  loadX(xr); term(0, 0); term(3, 3);
  loadX(xi); term(4, 5); term(7, 6);
#pragma unroll
  for (int o = 0; o < 2; ++o)
#pragma unroll
    for (int k = 0; k < 2; ++k)
      ut[((size_t)((p * 2 + o) * 128 + (q * 2 + k))) * 128 + b] = f2bf(Y[o * 2 + k]);
}

// ---------------------------------------------------------------------------
// Gather + transpose (R9)
// ---------------------------------------------------------------------------
__global__ __launch_bounds__(256) void k_gather(const unsigned short* __restrict__ ut,
                                                const int* __restrict__ r_index,
                                                unsigned short* __restrict__ yg) {
  __shared__ unsigned short ls[64][130];
  __shared__ int ridx[64];
  const int t = threadIdx.x;
  const int m0 = blockIdx.x * 64;
  if (t < 64) ridx[t] = r_index[m0 + t];
  __syncthreads();
  for (int it = 0; it < 32; ++it) {
    int idx = it * 256 + t;
    int ml = idx >> 7, b = idx & 127;
    ls[ml][b] = ut[(size_t)ridx[ml] * 128 + b];
  }
  __syncthreads();
  int b = t >> 1, half = t & 1;
#pragma unroll
  for (int c = 0; c < 4; ++c) {
    usx8 v;
#pragma unroll
    for (int e = 0; e < 8; ++e) v[e] = ls[half * 32 + c * 8 + e][b];
    *(usx8*)(yg + (size_t)b * 16384 + m0 + half * 32 + c * 8) = v;
  }
}

// ---------------------------------------------------------------------------
// GEMM v5: R9 gemm2 + triple-buffered B (depth-2). Grid (8,100), BK=64,
// 32 steps, bf16 partial.  LDS: As 2x128x72 (36.9KB) + Bs 3x64x72 (27.6KB).
// ---------------------------------------------------------------------------
#define G2_KC 8
#define G2_STEPS 32
#define G2_PITCH 72

__global__ __launch_bounds__(256) void k_gemm5(const unsigned short* __restrict__ yg,
                                               const float* __restrict__ cart,
                                               unsigned short* __restrict__ partial) {
  __shared__ unsigned short As[2][128][G2_PITCH];
  __shared__ unsigned short Bs[3][64][G2_PITCH];
  const int t = threadIdx.x;
  const int lane = t & 63, w = t >> 6;
  const int kc = blockIdx.x;
  const int c0 = blockIdx.y * 64;
  const int k0 = kc * 2048;

  fx4 acc[2][4];
#pragma unroll
  for (int i = 0; i < 2; ++i)
#pragma unroll
    for (int j = 0; j < 4; ++j) acc[i][j] = (fx4)0.f;

  auto ldA = [&](int rep, int kpos) -> usx8 {
    int c = t + rep * 256;
    return *(const usx8*)(yg + (size_t)(c >> 3) * 16384 + kpos + (c & 7) * 8);
  };
  auto stA = [&](int buf, int rep, usx8 v) {
    int c = t + rep * 256;
    *(usx8*)(&As[buf][c >> 3][(c & 7) * 8]) = v;
  };
  auto ldB = [&](int rep, int kpos, fx4* f0, fx4* f1) {
    int c = t + rep * 256;
    const float* p = cart + (size_t)(c0 + (c >> 3)) * 16384 + kpos + (c & 7) * 8;
    *f0 = *(const fx4*)p;
    *f1 = *(const fx4*)(p + 4);
  };
  auto stB = [&](int buf, int rep, fx4 f0, fx4 f1) {
    int c = t + rep * 256;
    usx8 v;
    v[0]=f2bf(f0[0]); v[1]=f2bf(f0[1]); v[2]=f2bf(f0[2]); v[3]=f2bf(f0[3]);
    v[4]=f2bf(f1[0]); v[5]=f2bf(f1[1]); v[6]=f2bf(f1[2]); v[7]=f2bf(f1[3]);
    *(usx8*)(&Bs[buf][c >> 3][(c & 7) * 8]) = v;
  };

  // prologue: B tile0 staged, tile1 held in regs; A tile0 staged.
  fx4 rB00, rB01, rB10, rB11;
  {
    usx8 a0 = ldA(0, k0), a1 = ldA(1, k0), a2 = ldA(2, k0), a3 = ldA(3, k0);
    fx4 b00, b01, b10, b11;
    ldB(0, k0, &b00, &b01); ldB(1, k0, &b10, &b11);
    ldB(0, k0 + 64, &rB00, &rB01); ldB(1, k0 + 64, &rB10, &rB11);
    stA(0, 0, a0); stA(0, 1, a1); stA(0, 2, a2); stA(0, 3, a3);
    stB(0, 0, b00, b01); stB(0, 1, b10, b11);
  }
  __syncthreads();

  for (int s = 0; s < G2_STEPS; ++s) {
    const int curA = s & 1, curB = s % 3;
    // (1) store B tile s+1 (aged one full step); issue B loads for s+2
    if (s + 1 < G2_STEPS) {
      stB((s + 1) % 3, 0, rB00, rB01); stB((s + 1) % 3, 1, rB10, rB11);
    }
    if (s + 2 < G2_STEPS) {
      int kpos = k0 + (s + 2) * 64;
      ldB(0, kpos, &rB00, &rB01); ldB(1, kpos, &rB10, &rB11);
    }
    // (2) A loads for s+1 (L2-resident; stored at step end = enough aging)
    usx8 av[4];
    const bool pfA = (s + 1 < G2_STEPS);
    if (pfA) {
      int kpos = k0 + (s + 1) * 64;
      av[0] = ldA(0, kpos); av[1] = ldA(1, kpos);
      av[2] = ldA(2, kpos); av[3] = ldA(3, kpos);
    }
    // (3) compute on current buffers
    sx8 af[2][2], bf[4][2];
#pragma unroll
    for (int mi = 0; mi < 2; ++mi)
#pragma unroll
      for (int kk = 0; kk < 2; ++kk)
        af[mi][kk] = *(const sx8*)(&As[curA][w * 32 + mi * 16 + (lane & 15)][kk * 32 + (lane >> 4) * 8]);
#pragma unroll
    for (int ni = 0; ni < 4; ++ni)
#pragma unroll
      for (int kk = 0; kk < 2; ++kk)
        bf[ni][kk] = *(const sx8*)(&Bs[curB][ni * 16 + (lane & 15)][kk * 32 + (lane >> 4) * 8]);
#pragma unroll
    for (int kk = 0; kk < 2; ++kk)
#pragma unroll
      for (int mi = 0; mi < 2; ++mi)
#pragma unroll
        for (int ni = 0; ni < 4; ++ni)
          acc[mi][ni] = __builtin_amdgcn_mfma_f32_16x16x32_bf16(af[mi][kk], bf[ni][kk], acc[mi][ni], 0, 0, 0);
    // (4) late A store
    if (pfA) {
      stA(curA ^ 1, 0, av[0]); stA(curA ^ 1, 1, av[1]);
      stA(curA ^ 1, 2, av[2]); stA(curA ^ 1, 3, av[3]);
    }
    __syncthreads();
  }

  // epilogue: partial[kc][b][c] bf16
#pragma unroll
  for (int mi = 0; mi < 2; ++mi) {
    int brow = w * 32 + mi * 16 + (lane >> 4) * 4;
#pragma unroll
    for (int ni = 0; ni < 4; ++ni) {
      int cc = c0 + ni * 16 + (lane & 15);
#pragma unroll
      for (int r = 0; r < 4; ++r)
        partial[((size_t)kc * 128 + brow + r) * 6400 + cc] = f2bf(acc[mi][ni][r]);
    }
  }
}

__global__ __launch_bounds__(256) void k_reduce2(const unsigned short* __restrict__ partial,
                                                 float* __restrict__ out) {
  int i = blockIdx.x * 256 + threadIdx.x;
  fx4 s = (fx4)0.f;
#pragma unroll
  for (int kc = 0; kc < G2_KC; ++kc) {
    usx4 v = *(const usx4*)(partial + (size_t)kc * 819200 + (size_t)i * 4);
    s[0] += bf2f(v[0]); s[1] += bf2f(v[1]); s[2] += bf2f(v[2]); s[3] += bf2f(v[3]);
  }
  *(fx4*)(out + (size_t)i * 4) = s;
}

// ---------------------------------------------------------------------------
extern "C" void kernel_launch(void* const* d_in, const int* in_sizes, int n_in,
                              void* d_out, int out_size, void* d_ws, size_t ws_size,
                              hipStream_t stream) {
  const float* x    = (const float*)d_in[0];
  const float* Vp   = (const float*)d_in[1];
  const float* Hp   = (const float*)d_in[2];
  const float* Mp   = (const float*)d_in[3];
  const float* Gp   = (const float*)d_in[4];
  const float* Up   = (const float*)d_in[5];
  const float* cart = (const float*)d_in[6];
  const int*   ridx = (const int*)d_in[7];
  float* out = (float*)d_out;
  unsigned short* hb = (unsigned short*)d_ws;

  const size_t PSZ = 4718592;
  f16* P0r = (f16*)(hb);
  f16* P0i = (f16*)(hb + PSZ);
  f16* P1r = (f16*)(hb + 2 * PSZ);
  f16* P1i = (f16*)(hb + 3 * PSZ);
  f16* xtr = (f16*)(hb + 4 * PSZ);
  f16* xti = (f16*)(hb + 4 * PSZ + 2097152);
  unsigned short* ut = hb + 4 * PSZ;
  unsigned short* yg = hb + 4 * PSZ + 2097152;
  unsigned short* partial = hb;

  const size_t HSZ = 8 * 32 * 36;

  k_transpose<<<dim3(128, 4), 256, 0, stream>>>(x, xtr, xti);
  k_vh<<<dim3(32, 32), 512, 0, stream>>>(xtr, xti, P0r, P0i, Vp, Hp + 0 * HSZ);
  k_hg<1><<<dim3(32, 32), 512, 0, stream>>>(P0r, P0i, P1r, P1i, Hp + 1 * HSZ);  // perm(l=4)
  k_hg<2><<<dim3(32, 32), 512, 0, stream>>>(P1r, P1i, P0r, P0i, Hp + 2 * HSZ);  // perm(l=3)
  k_mg<<<dim3(32, 32), 512, 0, stream>>>(P0r, P0i, P1r, P1i, Mp, Gp + 0 * HSZ); // switch+M123+G1
  k_hg<4><<<dim3(32, 32), 512, 0, stream>>>(P1r, P1i, P0r, P0i, Gp + 1 * HSZ);  // perm(l=2)
  k_hg<5><<<dim3(32, 32), 512, 0, stream>>>(P0r, P0i, P1r, P1i, Gp + 2 * HSZ);  // perm(l=1)
  k_u2<<<dim3(32, 32), 512, 0, stream>>>(P1r, P1i, ut, Up);                     // perm(l=0) inside
  k_gather<<<dim3(256), 256, 0, stream>>>(ut, ridx, yg);
  k_gemm5<<<dim3(G2_KC, 100), 256, 0, stream>>>(yg, cart, partial);
  k_reduce2<<<dim3(800), 256, 0, stream>>>(partial, out);
  (void)in_sizes; (void)n_in; (void)out_size; (void)ws_size;
}